// Round 1
// baseline (6073.626 us; speedup 1.0000x reference)
//
#include <hip/hip_runtime.h>
#include <stdint.h>

#define B_SZ  8192
#define S_DIM 512
#define H_DIM 2048
#define KIN   576
#define OUT_MS 4194304  // B*S

typedef unsigned short u16;
typedef u16   u16x8 __attribute__((ext_vector_type(8)));
typedef short s16x8 __attribute__((ext_vector_type(8)));
typedef float f32x4 __attribute__((ext_vector_type(4)));

__device__ __forceinline__ float b2f(u16 u) {
    union { unsigned int i; float f; } v; v.i = ((unsigned int)u) << 16; return v.f;
}
__device__ __forceinline__ u16 f2b(float f) {
    union { float f; unsigned int i; } v; v.f = f;
    unsigned int u = v.i;
    return (u16)((u + 0x7FFFu + ((u >> 16) & 1u)) >> 16);  // RNE
}

// CK-style generic->LDS pointer cast: low 32 bits of flat group address = LDS offset.
__device__ __forceinline__ void gload_lds16(const void* gp, void* lp) {
    __builtin_amdgcn_global_load_lds(
        (const __attribute__((address_space(1))) unsigned int*)gp,
        (__attribute__((address_space(3))) unsigned int*)(unsigned int)(uintptr_t)lp,
        16, 0, 0);
}

// ---------------- concat + cast to bf16: xb[b][0:512]=state, [512:576]=action ----
__global__ __launch_bounds__(256) void k_concat(
    const float* __restrict__ state, const float* __restrict__ action,
    u16* __restrict__ xb)
{
    int idx = blockIdx.x * 256 + threadIdx.x;          // exact grid: B*576/256
    int b = idx / KIN, c = idx - b * KIN;
    float v = (c < S_DIM) ? state[(size_t)b * S_DIM + c]
                          : action[(size_t)b * 64 + (c - S_DIM)];
    xb[idx] = f2b(v);
}

// ---------------- f32 [R][C] -> bf16 [C][R] (per-z matrix) ----------------------
__global__ __launch_bounds__(256) void k_transpose(
    const float* __restrict__ src, u16* __restrict__ dst, int R, int C)
{
    __shared__ float tile[32][33];
    const int tx = threadIdx.x, ty = threadIdx.y;
    const int c0 = blockIdx.x * 32, r0 = blockIdx.y * 32;
    const size_t mo = (size_t)blockIdx.z * R * C;
    src += mo; dst += mo;
#pragma unroll
    for (int j = 0; j < 4; ++j)
        tile[ty + j * 8][tx] = src[(size_t)(r0 + ty + j * 8) * C + c0 + tx];
    __syncthreads();
#pragma unroll
    for (int j = 0; j < 4; ++j)
        dst[(size_t)(c0 + ty + j * 8) * R + r0 + tx] = f2b(tile[tx][ty + j * 8]);
}

// ---------------- GEMM: C[M,N] = A[M,K](bf16) * Bt[N,K](bf16)^T ------------------
// m97 structure: 128x128 tile, BK=32, 256 thr (4 waves 2x2), 16x16x32 MFMA, acc 4x4.
// MODE 0: Z[idx] = bf16(acc + bias[n])
// MODE 1: c = state[idx] + acc + bias[n]; sum += c; sumsq += c*c   (N==512)
template<int MODE>
__global__ __launch_bounds__(256) void k_gemm(
    const u16* __restrict__ A, const u16* __restrict__ Bt,
    const float* __restrict__ bias, u16* __restrict__ Z,
    const float* __restrict__ st, float* __restrict__ sum_o, float* __restrict__ sq_o,
    int M, int N, int K)
{
    (void)M;
    __shared__ __align__(16) u16 As[128 * 32];
    __shared__ __align__(16) u16 Bs[128 * 32];
    const int t = threadIdx.x;
    const int lane = t & 63;
    const int wave = t >> 6;
    const int wr = wave >> 1, wc = wave & 1;
    const int m0 = blockIdx.x * 128, n0 = blockIdx.y * 128;
    const u16* Ab = A + (size_t)m0 * K;
    const u16* Bb = Bt + (size_t)n0 * K;

    f32x4 acc[4][4];
#pragma unroll
    for (int i = 0; i < 4; ++i)
#pragma unroll
        for (int j = 0; j < 4; ++j) acc[i][j] = (f32x4){0.f, 0.f, 0.f, 0.f};

    const int e0 = t * 8;                 // staging element idx, issue 0
    const int r0 = e0 >> 5, c0 = e0 & 31;
    const int e1 = e0 + 2048;             // issue 1
    const int r1 = e1 >> 5, c1 = e1 & 31;
    const int fr = lane & 15;
    const int fk = (lane >> 4) * 8;

    for (int k0 = 0; k0 < K; k0 += 32) {
        gload_lds16(Ab + (size_t)r0 * K + k0 + c0, &As[e0]);
        gload_lds16(Bb + (size_t)r0 * K + k0 + c0, &Bs[e0]);
        gload_lds16(Ab + (size_t)r1 * K + k0 + c1, &As[e1]);
        gload_lds16(Bb + (size_t)r1 * K + k0 + c1, &Bs[e1]);
        __syncthreads();
        s16x8 a[4], b[4];
#pragma unroll
        for (int i = 0; i < 4; ++i)
            a[i] = *(const s16x8*)&As[(wr * 64 + i * 16 + fr) * 32 + fk];
#pragma unroll
        for (int j = 0; j < 4; ++j)
            b[j] = *(const s16x8*)&Bs[(wc * 64 + j * 16 + fr) * 32 + fk];
#pragma unroll
        for (int i = 0; i < 4; ++i)
#pragma unroll
            for (int j = 0; j < 4; ++j)
                acc[i][j] = __builtin_amdgcn_mfma_f32_16x16x32_bf16(
                    a[i], b[j], acc[i][j], 0, 0, 0);
        __syncthreads();
    }

    const int rg = lane >> 4;  // C/D: col = lane&15, row = (lane>>4)*4 + reg
#pragma unroll
    for (int i = 0; i < 4; ++i) {
        const int rowb = m0 + wr * 64 + i * 16 + rg * 4;
#pragma unroll
        for (int j = 0; j < 4; ++j) {
            const int col = n0 + wc * 64 + j * 16 + fr;
            const float bv = bias[col];
#pragma unroll
            for (int r = 0; r < 4; ++r) {
                const size_t idx = (size_t)(rowb + r) * N + col;
                if (MODE == 0) {
                    Z[idx] = f2b(acc[i][j][r] + bv);
                } else {
                    const float c = st[idx] + acc[i][j][r] + bv;
                    sum_o[idx] += c;
                    sq_o[idx] += c * c;
                }
            }
        }
    }
}

// ---------------- LayerNorm + exact GELU (+ optional residual, in-place h) -------
__global__ __launch_bounds__(256) void k_ln(
    const u16* __restrict__ z, u16* __restrict__ h,
    const float* __restrict__ g, const float* __restrict__ be, int residual)
{
    const int row = blockIdx.x;
    const int t = threadIdx.x;
    const u16* zr = z + (size_t)row * H_DIM;
    u16* hr = h + (size_t)row * H_DIM;
    u16x8 zv = *(const u16x8*)&zr[t * 8];
    float v[8];
    float s = 0.f, q = 0.f;
#pragma unroll
    for (int j = 0; j < 8; ++j) { v[j] = b2f(zv[j]); s += v[j]; q += v[j] * v[j]; }
#pragma unroll
    for (int o = 32; o; o >>= 1) { s += __shfl_xor(s, o); q += __shfl_xor(q, o); }
    __shared__ float rs_[4], rq_[4];
    if ((t & 63) == 0) { rs_[t >> 6] = s; rq_[t >> 6] = q; }
    __syncthreads();
    s = rs_[0] + rs_[1] + rs_[2] + rs_[3];
    q = rq_[0] + rq_[1] + rq_[2] + rq_[3];
    const float mu = s * (1.0f / H_DIM);
    const float var = q * (1.0f / H_DIM) - mu * mu;
    const float rsg = rsqrtf(var + 1e-5f);
    u16x8 hv;
    if (residual) hv = *(const u16x8*)&hr[t * 8];
    u16x8 ov;
#pragma unroll
    for (int j = 0; j < 8; ++j) {
        const float y = (v[j] - mu) * rsg * g[t * 8 + j] + be[t * 8 + j];
        float ge = 0.5f * y * (1.0f + erff(y * 0.70710678118f));
        if (residual) ge += b2f(hv[j]);
        ov[j] = f2b(ge);
    }
    *(u16x8*)&hr[t * 8] = ov;
}

// ---------------- reward/done heads: one wave per batch row ----------------------
__global__ __launch_bounds__(256) void k_rewdone(
    const u16* __restrict__ h, const float* __restrict__ wr_, const float* __restrict__ wd_,
    const float* __restrict__ br, const float* __restrict__ bd,
    float* __restrict__ sum_rew, float* __restrict__ sum_done)
{
    const int t = threadIdx.x;
    const int lane = t & 63;
    const int b = blockIdx.x * 4 + (t >> 6);
    const u16* hrow = h + (size_t)b * H_DIM;
    float dr = 0.f, dd = 0.f;
#pragma unroll
    for (int j = 0; j < 4; ++j) {
        const int o = j * 512 + lane * 8;
        u16x8 hv = *(const u16x8*)&hrow[o];
#pragma unroll
        for (int k = 0; k < 8; ++k) {
            const float f = b2f(hv[k]);
            dr += f * wr_[o + k];
            dd += f * wd_[o + k];
        }
    }
#pragma unroll
    for (int o = 32; o; o >>= 1) { dr += __shfl_xor(dr, o); dd += __shfl_xor(dd, o); }
    if (lane == 0) {
        sum_rew[b] += dr + br[0];
        sum_done[b] += 1.0f / (1.0f + expf(-(dd + bd[0])));
    }
}

// ---------------- finalize: mean/var over E, assemble outputs --------------------
__global__ __launch_bounds__(256) void k_final(
    const float* __restrict__ sum_st, const float* __restrict__ sq_st,
    const float* __restrict__ sum_rew, const float* __restrict__ sum_done,
    float* __restrict__ out)
{
    const int b = blockIdx.x, t = threadIdx.x;
    float vs = 0.f;
#pragma unroll
    for (int k = 0; k < 2; ++k) {
        const int s = t + k * 256;
        const size_t i = (size_t)b * S_DIM + s;
        const float S1 = sum_st[i], S2 = sq_st[i];
        out[i] = S1 * 0.125f;                          // mean over E=8
        vs += (S2 - S1 * S1 * 0.125f) * (1.0f / 7.0f); // unbiased var (ddof=1)
    }
#pragma unroll
    for (int o = 32; o; o >>= 1) vs += __shfl_xor(vs, o);
    __shared__ float rv[4];
    if ((t & 63) == 0) rv[t >> 6] = vs;
    __syncthreads();
    if (t == 0) {
        const float tot = rv[0] + rv[1] + rv[2] + rv[3];
        out[OUT_MS + b] = sum_rew[b] * 0.125f;
        out[OUT_MS + B_SZ + b] = sum_done[b] * 0.125f;
        out[OUT_MS + 2 * B_SZ + b] = tot * (1.0f / S_DIM);
    }
}

extern "C" void kernel_launch(void* const* d_in, const int* in_sizes, int n_in,
                              void* d_out, int out_size, void* d_ws, size_t ws_size,
                              hipStream_t stream) {
    (void)in_sizes; (void)n_in; (void)out_size; (void)ws_size;
    const float* state   = (const float*)d_in[0];
    const float* action  = (const float*)d_in[1];
    const float* W_in    = (const float*)d_in[2];
    const float* b_in    = (const float*)d_in[3];
    const float* g_in    = (const float*)d_in[4];
    const float* be_in   = (const float*)d_in[5];
    const float* W_h     = (const float*)d_in[6];
    const float* b_h     = (const float*)d_in[7];
    const float* g_h     = (const float*)d_in[8];
    const float* be_h    = (const float*)d_in[9];
    const float* W_state = (const float*)d_in[10];
    const float* b_state = (const float*)d_in[11];
    const float* W_rew   = (const float*)d_in[12];
    const float* b_rew   = (const float*)d_in[13];
    const float* W_done  = (const float*)d_in[14];
    const float* b_done  = (const float*)d_in[15];
    float* out = (float*)d_out;

    char* ws = (char*)d_ws;
    size_t off = 0;
    auto alloc = [&](size_t bytes) -> void* {
        void* p = ws + off; off += (bytes + 255) & ~((size_t)255); return p;
    };
    u16*   xb      = (u16*)alloc((size_t)B_SZ * KIN * 2);
    u16*   Wt_in   = (u16*)alloc((size_t)8 * H_DIM * KIN * 2);
    u16*   Wt_h    = (u16*)alloc((size_t)24 * H_DIM * H_DIM * 2);
    u16*   Wt_st   = (u16*)alloc((size_t)8 * S_DIM * H_DIM * 2);
    u16*   hbuf    = (u16*)alloc((size_t)B_SZ * H_DIM * 2);
    u16*   zbuf    = (u16*)alloc((size_t)B_SZ * H_DIM * 2);
    float* sum_st  = (float*)alloc((size_t)B_SZ * S_DIM * 4);
    float* sq_st   = (float*)alloc((size_t)B_SZ * S_DIM * 4);
    float* sum_rew = (float*)alloc((size_t)B_SZ * 4);
    float* sum_done= (float*)alloc((size_t)B_SZ * 4);
    // sum_st..sum_done are contiguous (all sizes multiples of 256)
    hipMemsetAsync(sum_st, 0, (size_t)B_SZ * S_DIM * 4 * 2 + (size_t)B_SZ * 4 * 2, stream);

    k_concat<<<dim3((B_SZ * KIN) / 256), dim3(256), 0, stream>>>(state, action, xb);
    k_transpose<<<dim3(H_DIM / 32, KIN / 32, 8),   dim3(32, 8), 0, stream>>>(W_in, Wt_in, KIN, H_DIM);
    k_transpose<<<dim3(H_DIM / 32, H_DIM / 32, 24), dim3(32, 8), 0, stream>>>(W_h, Wt_h, H_DIM, H_DIM);
    k_transpose<<<dim3(S_DIM / 32, H_DIM / 32, 8), dim3(32, 8), 0, stream>>>(W_state, Wt_st, H_DIM, S_DIM);

    for (int e = 0; e < 8; ++e) {
        k_gemm<0><<<dim3(64, 16), dim3(256), 0, stream>>>(
            xb, Wt_in + (size_t)e * H_DIM * KIN, b_in + (size_t)e * H_DIM,
            zbuf, nullptr, nullptr, nullptr, B_SZ, H_DIM, KIN);
        k_ln<<<dim3(B_SZ), dim3(256), 0, stream>>>(
            zbuf, hbuf, g_in + (size_t)e * H_DIM, be_in + (size_t)e * H_DIM, 0);
        for (int l = 0; l < 3; ++l) {
            const size_t wi = (size_t)(e * 3 + l);
            k_gemm<0><<<dim3(64, 16), dim3(256), 0, stream>>>(
                hbuf, Wt_h + wi * H_DIM * H_DIM, b_h + wi * H_DIM,
                zbuf, nullptr, nullptr, nullptr, B_SZ, H_DIM, H_DIM);
            k_ln<<<dim3(B_SZ), dim3(256), 0, stream>>>(
                zbuf, hbuf, g_h + wi * H_DIM, be_h + wi * H_DIM, 1);
        }
        k_gemm<1><<<dim3(64, 4), dim3(256), 0, stream>>>(
            hbuf, Wt_st + (size_t)e * S_DIM * H_DIM, b_state + (size_t)e * S_DIM,
            nullptr, state, sum_st, sq_st, B_SZ, S_DIM, H_DIM);
        k_rewdone<<<dim3(B_SZ / 4), dim3(256), 0, stream>>>(
            hbuf, W_rew + (size_t)e * H_DIM, W_done + (size_t)e * H_DIM,
            b_rew + e, b_done + e, sum_rew, sum_done);
    }
    k_final<<<dim3(B_SZ), dim3(256), 0, stream>>>(sum_st, sq_st, sum_rew, sum_done, out);
}

// Round 2
// 4303.600 us; speedup vs baseline: 1.4113x; 1.4113x over previous
//
#include <hip/hip_runtime.h>
#include <stdint.h>

#define B_SZ  8192
#define S_DIM 512
#define H_DIM 2048
#define KIN   576
#define OUT_MS 4194304  // B*S

typedef unsigned short u16;
typedef u16   u16x8 __attribute__((ext_vector_type(8)));
typedef short s16x8 __attribute__((ext_vector_type(8)));
typedef float f32x4 __attribute__((ext_vector_type(4)));

__device__ __forceinline__ float b2f(u16 u) {
    union { unsigned int i; float f; } v; v.i = ((unsigned int)u) << 16; return v.f;
}
__device__ __forceinline__ u16 f2b(float f) {
    union { float f; unsigned int i; } v; v.f = f;
    unsigned int u = v.i;
    return (u16)((u + 0x7FFFu + ((u >> 16) & 1u)) >> 16);  // RNE
}

__device__ __forceinline__ void gload_lds16(const void* gp, void* lp) {
    __builtin_amdgcn_global_load_lds(
        (const __attribute__((address_space(1))) unsigned int*)gp,
        (__attribute__((address_space(3))) unsigned int*)(unsigned int)(uintptr_t)lp,
        16, 0, 0);
}

#define MFMA __builtin_amdgcn_mfma_f32_16x16x32_bf16

// ---------------- concat + cast to bf16 ------------------------------------
__global__ __launch_bounds__(256) void k_concat(
    const float* __restrict__ state, const float* __restrict__ action,
    u16* __restrict__ xb)
{
    int idx = blockIdx.x * 256 + threadIdx.x;
    int b = idx / KIN, c = idx - b * KIN;
    float v = (c < S_DIM) ? state[(size_t)b * S_DIM + c]
                          : action[(size_t)b * 64 + (c - S_DIM)];
    xb[idx] = f2b(v);
}

// ---------------- f32 [R][C] -> bf16 [C][R] (per-z matrix) -------------------
__global__ __launch_bounds__(256) void k_transpose(
    const float* __restrict__ src, u16* __restrict__ dst, int R, int C)
{
    __shared__ float tile[32][33];
    const int tx = threadIdx.x, ty = threadIdx.y;
    const int c0 = blockIdx.x * 32, r0 = blockIdx.y * 32;
    const size_t mo = (size_t)blockIdx.z * R * C;
    src += mo; dst += mo;
#pragma unroll
    for (int j = 0; j < 4; ++j)
        tile[ty + j * 8][tx] = src[(size_t)(r0 + ty + j * 8) * C + c0 + tx];
    __syncthreads();
#pragma unroll
    for (int j = 0; j < 4; ++j)
        dst[(size_t)(c0 + ty + j * 8) * R + r0 + tx] = f2b(tile[tx][ty + j * 8]);
}

// ---------------- 256x256 8-phase GEMM (T1+T2+T3/T4+T5) ---------------------
// C[M,N] = A[M,K](bf16) * Bt[N,K](bf16)^T ; 512 thr = 8 waves (2M x 4N),
// BK=64, LDS 128KiB dbuf, st-swizzle (col ^= (row&7)*8 elems) on both sides,
// counted vmcnt (4/2) per K-tile, setprio around MFMA clusters.
// MODE 0: Z(u16)[row*N+col] = bf16(acc+bias)
// MODE 1: P(f32)[bz*sZe + row*N+col] = state + acc + bias      (N==512)
// MODE 2: c = state+acc+bias; sum_o += c; sq_o += c*c (non-atomic, seq e)
template<int MODE>
__global__ __launch_bounds__(512, 2) void k_gemm256(
    const u16* __restrict__ A, size_t sAe,
    const u16* __restrict__ Bt, size_t sBe,
    const float* __restrict__ bias, int sbE,
    void* __restrict__ Zv, size_t sZe,
    const float* __restrict__ st, float* __restrict__ sum_o, float* __restrict__ sq_o,
    int N, int K)
{
    __shared__ __align__(16) u16 lds[2][32768];   // [buf][A 16384 | B 16384]
    const int t = threadIdx.x;
    const int lane = t & 63;
    const int wid = t >> 6;
    const int wm = wid >> 2, wn = wid & 3;

    // XCD-aware swizzle (nwg % 8 == 0 for all our grids)
    const int gx = gridDim.x, gy = gridDim.y;
    const int linb = blockIdx.x + gx * (blockIdx.y + gy * blockIdx.z);
    const int nwg = gx * gy * gridDim.z;
    const int q8 = nwg >> 3;
    const int swz = (linb & 7) * q8 + (linb >> 3);
    const int bx = swz % gx;
    const int tmp = swz / gx;
    const int by = tmp % gy;
    const int bz = tmp / gy;
    const int m0 = bx * 256, n0 = by * 256;

    const u16* Ab = A + (size_t)bz * sAe + (size_t)m0 * K;
    const u16* Bb = Bt + (size_t)bz * sBe + (size_t)n0 * K;

    // staging: round = 64 rows x 64 cols of one matrix; thread covers 16B.
    // LDS linear (row, (t&7)*16B) holds global col pre-swizzled by row&7.
    const int srow = t >> 3;                       // 0..63 within round
    const int scol = (((t & 7) ^ (srow & 7)) * 8); // element col in tile
    const u16* gA = Ab + (size_t)srow * K + scol;
    const u16* gB = Bb + (size_t)srow * K + scol;
    u16* lbase = &lds[0][0];
    const int ldst = srow * 64 + (t & 7) * 8;      // element offset in slab
    const int NT = K >> 6;

    auto STAGE = [&](int kt, int d, int mat, int r) {
        const u16* gp = (mat ? gB : gA) + (size_t)(r * 64) * K + kt * 64;
        u16* lp = lbase + d * 32768 + mat * 16384 + r * 4096 + ldst;
        gload_lds16(gp, lp);
    };

    // fragment LDS byte offsets (within matrix slab), swizzled reads
    const int fr = lane & 15, hi = lane >> 4;
    const int cswz = (fr & 7) << 4;
    const int ac0 = (hi * 16) ^ cswz;              // k-half 0
    const int ac1 = (64 + hi * 16) ^ cswz;         // k-half 1
    const int ar0 = (wm * 128 + fr) * 128;         // mi'=0 (q adds q*4096)
    const int ar1 = (wm * 128 + 16 + fr) * 128;    // mi'=1
    int boff[4][2];
#pragma unroll
    for (int nj = 0; nj < 4; ++nj) {
        const int br_ = (wn * 64 + nj * 16 + fr) * 128;
        boff[nj][0] = br_ + ac0;
        boff[nj][1] = br_ + ac1;
    }

    f32x4 acc[8][4];
#pragma unroll
    for (int i = 0; i < 8; ++i)
#pragma unroll
        for (int j = 0; j < 4; ++j) acc[i][j] = (f32x4){0.f, 0.f, 0.f, 0.f};

    // prologue: K-tile 0 into buf 0, order B0 B1 B2 B3 A0 A2 A1 A3
    STAGE(0, 0, 1, 0); STAGE(0, 0, 1, 1); STAGE(0, 0, 1, 2); STAGE(0, 0, 1, 3);
    STAGE(0, 0, 0, 0); STAGE(0, 0, 0, 2); STAGE(0, 0, 0, 1); STAGE(0, 0, 0, 3);
    asm volatile("s_waitcnt vmcnt(2)" ::: "memory");   // B*, A0, A2 landed
    __builtin_amdgcn_sched_barrier(0);
    __builtin_amdgcn_s_barrier();

    s16x8 bfrag[4][2];

    for (int kt = 0; kt < NT; ++kt) {
        const int d = kt & 1;
        const char* LA = (const char*)lbase + d * 65536;
        const char* LB = LA + 32768;
        const int nx = d ^ 1;
        const bool hn = (kt + 1 < NT);

        // ---- phase 0 (q=0): read all B + A-q0; stage next B0,B1
        {
            s16x8 a00, a01, a10, a11;
#pragma unroll
            for (int nj = 0; nj < 4; ++nj) {
                bfrag[nj][0] = *(const s16x8*)(LB + boff[nj][0]);
                bfrag[nj][1] = *(const s16x8*)(LB + boff[nj][1]);
            }
            a00 = *(const s16x8*)(LA + ar0 + ac0);
            a01 = *(const s16x8*)(LA + ar0 + ac1);
            a10 = *(const s16x8*)(LA + ar1 + ac0);
            a11 = *(const s16x8*)(LA + ar1 + ac1);
            if (hn) { STAGE(kt + 1, nx, 1, 0); STAGE(kt + 1, nx, 1, 1); }
            __builtin_amdgcn_s_barrier();
            __builtin_amdgcn_s_setprio(1);
#pragma unroll
            for (int nj = 0; nj < 4; ++nj) {
                acc[0][nj] = MFMA(a00, bfrag[nj][0], acc[0][nj], 0, 0, 0);
                acc[0][nj] = MFMA(a01, bfrag[nj][1], acc[0][nj], 0, 0, 0);
                acc[1][nj] = MFMA(a10, bfrag[nj][0], acc[1][nj], 0, 0, 0);
                acc[1][nj] = MFMA(a11, bfrag[nj][1], acc[1][nj], 0, 0, 0);
            }
            __builtin_amdgcn_s_setprio(0);
            __builtin_amdgcn_s_barrier();
        }
        // ---- phase 1 (q=1): A-q1; stage next B2,B3; W1
        {
            s16x8 a00 = *(const s16x8*)(LA + 4096 + ar0 + ac0);
            s16x8 a01 = *(const s16x8*)(LA + 4096 + ar0 + ac1);
            s16x8 a10 = *(const s16x8*)(LA + 4096 + ar1 + ac0);
            s16x8 a11 = *(const s16x8*)(LA + 4096 + ar1 + ac1);
            if (hn) { STAGE(kt + 1, nx, 1, 2); STAGE(kt + 1, nx, 1, 3); }
            __builtin_amdgcn_s_barrier();
            __builtin_amdgcn_s_setprio(1);
#pragma unroll
            for (int nj = 0; nj < 4; ++nj) {
                acc[2][nj] = MFMA(a00, bfrag[nj][0], acc[2][nj], 0, 0, 0);
                acc[2][nj] = MFMA(a01, bfrag[nj][1], acc[2][nj], 0, 0, 0);
                acc[3][nj] = MFMA(a10, bfrag[nj][0], acc[3][nj], 0, 0, 0);
                acc[3][nj] = MFMA(a11, bfrag[nj][1], acc[3][nj], 0, 0, 0);
            }
            __builtin_amdgcn_s_setprio(0);
            // W1: this tile's A1,A3 must be in LDS before phase-2 reads.
            if (hn) { asm volatile("s_waitcnt vmcnt(4)" ::: "memory"); }
            else    { asm volatile("s_waitcnt vmcnt(0)" ::: "memory"); }
            __builtin_amdgcn_sched_barrier(0);
            __builtin_amdgcn_s_barrier();
        }
        // ---- phase 2 (q=2): A-q2; stage next A0,A2
        {
            s16x8 a00 = *(const s16x8*)(LA + 8192 + ar0 + ac0);
            s16x8 a01 = *(const s16x8*)(LA + 8192 + ar0 + ac1);
            s16x8 a10 = *(const s16x8*)(LA + 8192 + ar1 + ac0);
            s16x8 a11 = *(const s16x8*)(LA + 8192 + ar1 + ac1);
            if (hn) { STAGE(kt + 1, nx, 0, 0); STAGE(kt + 1, nx, 0, 2); }
            __builtin_amdgcn_s_barrier();
            __builtin_amdgcn_s_setprio(1);
#pragma unroll
            for (int nj = 0; nj < 4; ++nj) {
                acc[4][nj] = MFMA(a00, bfrag[nj][0], acc[4][nj], 0, 0, 0);
                acc[4][nj] = MFMA(a01, bfrag[nj][1], acc[4][nj], 0, 0, 0);
                acc[5][nj] = MFMA(a10, bfrag[nj][0], acc[5][nj], 0, 0, 0);
                acc[5][nj] = MFMA(a11, bfrag[nj][1], acc[5][nj], 0, 0, 0);
            }
            __builtin_amdgcn_s_setprio(0);
            __builtin_amdgcn_s_barrier();
        }
        // ---- phase 3 (q=3): A-q3; stage next A1,A3; W2
        {
            s16x8 a00 = *(const s16x8*)(LA + 12288 + ar0 + ac0);
            s16x8 a01 = *(const s16x8*)(LA + 12288 + ar0 + ac1);
            s16x8 a10 = *(const s16x8*)(LA + 12288 + ar1 + ac0);
            s16x8 a11 = *(const s16x8*)(LA + 12288 + ar1 + ac1);
            if (hn) { STAGE(kt + 1, nx, 0, 1); STAGE(kt + 1, nx, 0, 3); }
            __builtin_amdgcn_s_barrier();
            __builtin_amdgcn_s_setprio(1);
#pragma unroll
            for (int nj = 0; nj < 4; ++nj) {
                acc[6][nj] = MFMA(a00, bfrag[nj][0], acc[6][nj], 0, 0, 0);
                acc[6][nj] = MFMA(a01, bfrag[nj][1], acc[6][nj], 0, 0, 0);
                acc[7][nj] = MFMA(a10, bfrag[nj][0], acc[7][nj], 0, 0, 0);
                acc[7][nj] = MFMA(a11, bfrag[nj][1], acc[7][nj], 0, 0, 0);
            }
            __builtin_amdgcn_s_setprio(0);
            // W2: next tile's B*,A0,A2 landed before its phase-0 reads.
            if (hn) {
                asm volatile("s_waitcnt vmcnt(2)" ::: "memory");
                __builtin_amdgcn_sched_barrier(0);
            }
            __builtin_amdgcn_s_barrier();
        }
    }

    // epilogue
    const float* biasp = bias + (size_t)bz * sbE;
#pragma unroll
    for (int mi = 0; mi < 8; ++mi) {
        const int rowb = m0 + wm * 128 + mi * 16 + hi * 4;
#pragma unroll
        for (int nj = 0; nj < 4; ++nj) {
            const int col = n0 + wn * 64 + nj * 16 + fr;
            const float bv = biasp[col];
#pragma unroll
            for (int r = 0; r < 4; ++r) {
                const int row = rowb + r;
                const size_t idx = (size_t)row * N + col;
                if (MODE == 0) {
                    ((u16*)Zv)[(size_t)bz * sZe + idx] = f2b(acc[mi][nj][r] + bv);
                } else if (MODE == 1) {
                    const float c = st[idx] + acc[mi][nj][r] + bv;
                    ((float*)Zv)[(size_t)bz * sZe + idx] = c;
                } else {
                    const float c = st[idx] + acc[mi][nj][r] + bv;
                    sum_o[idx] += c;
                    sq_o[idx] += c * c;
                }
            }
        }
    }
}

// ---------------- LayerNorm + exact GELU (+residual), wave-per-row ----------
__global__ __launch_bounds__(256) void k_ln(
    const u16* __restrict__ z, u16* __restrict__ h,
    const float* __restrict__ g, const float* __restrict__ be,
    int egb, int residual)
{
    const int lane = threadIdx.x & 63;
    const int w = threadIdx.x >> 6;
    const int e = blockIdx.z;
    const int row = blockIdx.x * 4 + w;
    const size_t base = ((size_t)e * B_SZ + row) * H_DIM;
    const u16* zr = z + base;
    u16* hr = h + base;
    const float* gp = g + (size_t)e * egb;
    const float* bp = be + (size_t)e * egb;

    float v[32];
    float s = 0.f, q = 0.f;
#pragma unroll
    for (int j = 0; j < 4; ++j) {
        u16x8 zv = *(const u16x8*)&zr[j * 512 + lane * 8];
#pragma unroll
        for (int k = 0; k < 8; ++k) {
            float f = b2f(zv[k]); v[j * 8 + k] = f; s += f; q += f * f;
        }
    }
#pragma unroll
    for (int o = 32; o; o >>= 1) { s += __shfl_xor(s, o); q += __shfl_xor(q, o); }
    const float mu = s * (1.0f / H_DIM);
    const float rsg = rsqrtf(q * (1.0f / H_DIM) - mu * mu + 1e-5f);
#pragma unroll
    for (int j = 0; j < 4; ++j) {
        const int c = j * 512 + lane * 8;
        u16x8 hv;
        if (residual) hv = *(const u16x8*)&hr[c];
        u16x8 ov;
#pragma unroll
        for (int k = 0; k < 8; ++k) {
            const float y = (v[j * 8 + k] - mu) * rsg * gp[c + k] + bp[c + k];
            float ge = 0.5f * y * (1.0f + erff(y * 0.70710678118f));
            if (residual) ge += b2f(hv[k]);
            ov[k] = f2b(ge);
        }
        *(u16x8*)&hr[c] = ov;
    }
}

// ---------------- reward/done heads: wave per batch row, atomics over e ------
__global__ __launch_bounds__(256) void k_rewdone(
    const u16* __restrict__ hB, const float* __restrict__ Wr, const float* __restrict__ Wd,
    const float* __restrict__ br, const float* __restrict__ bd,
    float* __restrict__ sum_rew, float* __restrict__ sum_done)
{
    const int e = blockIdx.z;
    const int lane = threadIdx.x & 63;
    const int b = blockIdx.x * 4 + (threadIdx.x >> 6);
    const u16* hrow = hB + ((size_t)e * B_SZ + b) * H_DIM;
    const float* wr_ = Wr + (size_t)e * H_DIM;
    const float* wd_ = Wd + (size_t)e * H_DIM;
    float dr = 0.f, dd = 0.f;
#pragma unroll
    for (int j = 0; j < 4; ++j) {
        const int o = j * 512 + lane * 8;
        u16x8 hv = *(const u16x8*)&hrow[o];
#pragma unroll
        for (int k = 0; k < 8; ++k) {
            const float f = b2f(hv[k]);
            dr += f * wr_[o + k];
            dd += f * wd_[o + k];
        }
    }
#pragma unroll
    for (int o = 32; o; o >>= 1) { dr += __shfl_xor(dr, o); dd += __shfl_xor(dd, o); }
    if (lane == 0) {
        atomicAdd(&sum_rew[b], dr + br[e]);
        atomicAdd(&sum_done[b], 1.0f / (1.0f + expf(-(dd + bd[e]))));
    }
}

// ---------------- finalize: mean/var over E ---------------------------------
template<int FB>
__global__ __launch_bounds__(256) void k_final(
    const float* __restrict__ P, const float* __restrict__ sum_st,
    const float* __restrict__ sq_st, const float* __restrict__ sum_rew,
    const float* __restrict__ sum_done, float* __restrict__ out)
{
    const int b = blockIdx.x, t = threadIdx.x;
    float vs = 0.f;
#pragma unroll
    for (int k = 0; k < 2; ++k) {
        const int s = t + k * 256;
        const size_t i = (size_t)b * S_DIM + s;
        float S1, S2;
        if (FB == 0) {
            S1 = 0.f; S2 = 0.f;
#pragma unroll
            for (int e = 0; e < 8; ++e) {
                const float c = P[(size_t)e * OUT_MS + i];
                S1 += c; S2 += c * c;
            }
        } else { S1 = sum_st[i]; S2 = sq_st[i]; }
        out[i] = S1 * 0.125f;
        vs += (S2 - S1 * S1 * 0.125f) * (1.0f / 7.0f);
    }
#pragma unroll
    for (int o = 32; o; o >>= 1) vs += __shfl_xor(vs, o);
    __shared__ float rv[4];
    if ((t & 63) == 0) rv[t >> 6] = vs;
    __syncthreads();
    if (t == 0) {
        const float tot = rv[0] + rv[1] + rv[2] + rv[3];
        out[OUT_MS + b] = sum_rew[b] * 0.125f;
        out[OUT_MS + B_SZ + b] = sum_done[b] * 0.125f;
        out[OUT_MS + 2 * B_SZ + b] = tot * (1.0f / S_DIM);
    }
}

extern "C" void kernel_launch(void* const* d_in, const int* in_sizes, int n_in,
                              void* d_out, int out_size, void* d_ws, size_t ws_size,
                              hipStream_t stream) {
    (void)in_sizes; (void)n_in; (void)out_size;
    const float* state   = (const float*)d_in[0];
    const float* action  = (const float*)d_in[1];
    const float* W_in    = (const float*)d_in[2];
    const float* b_in    = (const float*)d_in[3];
    const float* g_in    = (const float*)d_in[4];
    const float* be_in   = (const float*)d_in[5];
    const float* W_h     = (const float*)d_in[6];
    const float* b_h     = (const float*)d_in[7];
    const float* g_h     = (const float*)d_in[8];
    const float* be_h    = (const float*)d_in[9];
    const float* W_state = (const float*)d_in[10];
    const float* b_state = (const float*)d_in[11];
    const float* b_rew   = (const float*)d_in[13];
    const float* W_rew   = (const float*)d_in[12];
    const float* W_done  = (const float*)d_in[14];
    const float* b_done  = (const float*)d_in[15];
    float* out = (float*)d_out;

    char* ws = (char*)d_ws;
    size_t off = 0;
    auto alloc = [&](size_t bytes) -> void* {
        void* p = ws + off; off += (bytes + 255) & ~((size_t)255); return p;
    };
    const size_t BH = (size_t)B_SZ * H_DIM;       // 16777216
    u16*   xb      = (u16*)alloc((size_t)B_SZ * KIN * 2);
    u16*   Wt_in   = (u16*)alloc((size_t)8 * H_DIM * KIN * 2);
    u16*   Wt_h    = (u16*)alloc((size_t)24 * H_DIM * H_DIM * 2);
    u16*   Wt_st   = (u16*)alloc((size_t)8 * S_DIM * H_DIM * 2);
    float* sum_st  = (float*)alloc((size_t)B_SZ * S_DIM * 4);
    float* sq_st   = (float*)alloc((size_t)B_SZ * S_DIM * 4);
    float* sum_rew = (float*)alloc((size_t)B_SZ * 4);
    float* sum_done= (float*)alloc((size_t)B_SZ * 4);
    const size_t fixed = off;
    const int EB = (ws_size >= fixed + 2ULL * 8 * BH * 2) ? 8 : 1;
    u16*   hbuf    = (u16*)alloc((size_t)EB * BH * 2);
    u16*   zbuf    = (u16*)alloc((size_t)EB * BH * 2);
    float* Pbuf    = (float*)zbuf;   // batched: f32 next_states alias (dead zbuf)

    if (EB == 8) {
        hipMemsetAsync(sum_rew, 0, 2 * (size_t)B_SZ * 4, stream);
    } else {
        hipMemsetAsync(sum_st, 0, (2 * (size_t)B_SZ * S_DIM + 2 * B_SZ) * 4, stream);
    }

    k_concat<<<dim3((B_SZ * KIN) / 256), dim3(256), 0, stream>>>(state, action, xb);
    k_transpose<<<dim3(H_DIM / 32, KIN / 32, 8),    dim3(32, 8), 0, stream>>>(W_in, Wt_in, KIN, H_DIM);
    k_transpose<<<dim3(H_DIM / 32, H_DIM / 32, 24), dim3(32, 8), 0, stream>>>(W_h, Wt_h, H_DIM, H_DIM);
    k_transpose<<<dim3(S_DIM / 32, H_DIM / 32, 8),  dim3(32, 8), 0, stream>>>(W_state, Wt_st, H_DIM, S_DIM);

    for (int e0 = 0; e0 < 8; e0 += EB) {
        const dim3 gH(32, 8, EB), gS(32, 2, EB), gL(2048, 1, EB);
        k_gemm256<0><<<gH, 512, 0, stream>>>(
            xb, 0, Wt_in + (size_t)e0 * H_DIM * KIN, (size_t)H_DIM * KIN,
            b_in + (size_t)e0 * H_DIM, H_DIM, zbuf, BH,
            nullptr, nullptr, nullptr, H_DIM, KIN);
        k_ln<<<gL, 256, 0, stream>>>(zbuf, hbuf,
            g_in + (size_t)e0 * H_DIM, be_in + (size_t)e0 * H_DIM, H_DIM, 0);
        for (int l = 0; l < 3; ++l) {
            k_gemm256<0><<<gH, 512, 0, stream>>>(
                hbuf, BH, Wt_h + ((size_t)e0 * 3 + l) * H_DIM * H_DIM, (size_t)3 * H_DIM * H_DIM,
                b_h + (size_t)(e0 * 3 + l) * H_DIM, 3 * H_DIM, zbuf, BH,
                nullptr, nullptr, nullptr, H_DIM, H_DIM);
            k_ln<<<gL, 256, 0, stream>>>(zbuf, hbuf,
                g_h + (size_t)(e0 * 3 + l) * H_DIM, be_h + (size_t)(e0 * 3 + l) * H_DIM,
                3 * H_DIM, 1);
        }
        if (EB == 8) {
            k_gemm256<1><<<gS, 512, 0, stream>>>(
                hbuf, BH, Wt_st, (size_t)S_DIM * H_DIM,
                b_state, S_DIM, (void*)Pbuf, (size_t)OUT_MS,
                state, nullptr, nullptr, S_DIM, H_DIM);
        } else {
            k_gemm256<2><<<gS, 512, 0, stream>>>(
                hbuf, BH, Wt_st + (size_t)e0 * S_DIM * H_DIM, (size_t)S_DIM * H_DIM,
                b_state + (size_t)e0 * S_DIM, S_DIM, (void*)zbuf, 0,
                state, sum_st, sq_st, S_DIM, H_DIM);
        }
        k_rewdone<<<gL, 256, 0, stream>>>(hbuf,
            W_rew + (size_t)e0 * H_DIM, W_done + (size_t)e0 * H_DIM,
            b_rew + e0, b_done + e0, sum_rew, sum_done);
    }
    if (EB == 8)
        k_final<0><<<dim3(B_SZ), dim3(256), 0, stream>>>(Pbuf, nullptr, nullptr, sum_rew, sum_done, out);
    else
        k_final<1><<<dim3(B_SZ), dim3(256), 0, stream>>>(nullptr, sum_st, sq_st, sum_rew, sum_done, out);
}

// Round 3
// 4058.541 us; speedup vs baseline: 1.4965x; 1.0604x over previous
//
#include <hip/hip_runtime.h>
#include <stdint.h>

#define B_SZ  8192
#define S_DIM 512
#define H_DIM 2048
#define KIN   576
#define OUT_MS 4194304  // B*S

typedef unsigned short u16;
typedef u16   u16x8 __attribute__((ext_vector_type(8)));
typedef short s16x8 __attribute__((ext_vector_type(8)));
typedef float f32x4 __attribute__((ext_vector_type(4)));

__device__ __forceinline__ float b2f(u16 u) {
    union { unsigned int i; float f; } v; v.i = ((unsigned int)u) << 16; return v.f;
}
__device__ __forceinline__ u16 f2b(float f) {
    union { float f; unsigned int i; } v; v.f = f;
    unsigned int u = v.i;
    return (u16)((u + 0x7FFFu + ((u >> 16) & 1u)) >> 16);  // RNE
}

__device__ __forceinline__ void gload_lds16(const void* gp, void* lp) {
    __builtin_amdgcn_global_load_lds(
        (const __attribute__((address_space(1))) unsigned int*)gp,
        (__attribute__((address_space(3))) unsigned int*)(unsigned int)(uintptr_t)lp,
        16, 0, 0);
}

#define MFMA __builtin_amdgcn_mfma_f32_16x16x32_bf16

// ---------------- concat + cast to bf16 ------------------------------------
__global__ __launch_bounds__(256) void k_concat(
    const float* __restrict__ state, const float* __restrict__ action,
    u16* __restrict__ xb)
{
    int idx = blockIdx.x * 256 + threadIdx.x;
    int b = idx / KIN, c = idx - b * KIN;
    float v = (c < S_DIM) ? state[(size_t)b * S_DIM + c]
                          : action[(size_t)b * 64 + (c - S_DIM)];
    xb[idx] = f2b(v);
}

// ---------------- f32 [R][C] -> bf16 [C][R] (per-z matrix) -------------------
__global__ __launch_bounds__(256) void k_transpose(
    const float* __restrict__ src, u16* __restrict__ dst, int R, int C)
{
    __shared__ float tile[32][33];
    const int tx = threadIdx.x, ty = threadIdx.y;
    const int c0 = blockIdx.x * 32, r0 = blockIdx.y * 32;
    const size_t mo = (size_t)blockIdx.z * R * C;
    src += mo; dst += mo;
#pragma unroll
    for (int j = 0; j < 4; ++j)
        tile[ty + j * 8][tx] = src[(size_t)(r0 + ty + j * 8) * C + c0 + tx];
    __syncthreads();
#pragma unroll
    for (int j = 0; j < 4; ++j)
        dst[(size_t)(c0 + ty + j * 8) * R + r0 + tx] = f2b(tile[tx][ty + j * 8]);
}

// ---------------- 256x256 8-phase GEMM (T1+T2+T3/T4+T5) ---------------------
// C[M,N] = A[M,K](bf16) * Bt[N,K](bf16)^T ; 512 thr = 8 waves (2M x 4N),
// BK=64, LDS 128KiB dbuf, st-swizzle (col ^= (row&7)*8 elems) on both sides,
// counted vmcnt (4/2) per K-tile, setprio around MFMA clusters.
// Block swizzle: e-major execution (bz slowest), per-XCD contiguous bx, by
// fastest -> per-e working set (A panels L2, weights L3-hot).
// MODE 0: Z(u16)[row*N+col] = bf16(acc+bias)
// MODE 1: P(f32)[bz*sZe + row*N+col] = state + acc + bias      (N==512)
// MODE 2: c = state+acc+bias; sum_o += c; sq_o += c*c (non-atomic, seq e)
template<int MODE>
__global__ __launch_bounds__(512, 2) void k_gemm256(
    const u16* __restrict__ A, size_t sAe,
    const u16* __restrict__ Bt, size_t sBe,
    const float* __restrict__ bias, int sbE,
    void* __restrict__ Zv, size_t sZe,
    const float* __restrict__ st, float* __restrict__ sum_o, float* __restrict__ sq_o,
    int N, int K)
{
    __shared__ __align__(16) u16 lds[2][32768];   // [buf][A 16384 | B 16384]
    const int t = threadIdx.x;
    const int lane = t & 63;
    const int wid = t >> 6;
    const int wm = wid >> 2, wn = wid & 3;

    // locality swizzle: requires gx % 8 == 0 (here gx == 32).
    const int gx = gridDim.x, gy = gridDim.y;
    const int linb = blockIdx.x + gx * (blockIdx.y + gy * blockIdx.z);
    const int x  = linb & 7;            // XCD (round-robin dispatch assumption)
    const int s  = linb >> 3;           // slot within XCD, increasing in time
    const int m_ = (gx * gy) >> 3;      // slots per ensemble per XCD
    const int bz = s / m_;
    const int r_ = s - bz * m_;
    const int p_ = r_ / gy;
    const int by = r_ - p_ * gy;
    const int bx = x * (gx >> 3) + p_;
    const int m0 = bx * 256, n0 = by * 256;

    const u16* Ab = A + (size_t)bz * sAe + (size_t)m0 * K;
    const u16* Bb = Bt + (size_t)bz * sBe + (size_t)n0 * K;

    // staging: round = 64 rows x 64 cols of one matrix; thread covers 16B.
    // LDS linear (row, (t&7)*16B) holds global col pre-swizzled by row&7.
    const int srow = t >> 3;                       // 0..63 within round
    const int scol = (((t & 7) ^ (srow & 7)) * 8); // element col in tile
    const u16* gA = Ab + (size_t)srow * K + scol;
    const u16* gB = Bb + (size_t)srow * K + scol;
    u16* lbase = &lds[0][0];
    const int ldst = srow * 64 + (t & 7) * 8;      // element offset in slab
    const int NT = K >> 6;

    auto STAGE = [&](int kt, int d, int mat, int r) {
        const u16* gp = (mat ? gB : gA) + (size_t)(r * 64) * K + kt * 64;
        u16* lp = lbase + d * 32768 + mat * 16384 + r * 4096 + ldst;
        gload_lds16(gp, lp);
    };

    // fragment LDS byte offsets (within matrix slab), swizzled reads
    const int fr = lane & 15, hi = lane >> 4;
    const int cswz = (fr & 7) << 4;
    const int ac0 = (hi * 16) ^ cswz;              // k-half 0
    const int ac1 = (64 + hi * 16) ^ cswz;         // k-half 1
    const int ar0 = (wm * 128 + fr) * 128;         // mi'=0 (q adds q*4096)
    const int ar1 = (wm * 128 + 16 + fr) * 128;    // mi'=1
    int boff[4][2];
#pragma unroll
    for (int nj = 0; nj < 4; ++nj) {
        const int br_ = (wn * 64 + nj * 16 + fr) * 128;
        boff[nj][0] = br_ + ac0;
        boff[nj][1] = br_ + ac1;
    }

    f32x4 acc[8][4];
#pragma unroll
    for (int i = 0; i < 8; ++i)
#pragma unroll
        for (int j = 0; j < 4; ++j) acc[i][j] = (f32x4){0.f, 0.f, 0.f, 0.f};

    // prologue: K-tile 0 into buf 0, order B0 B1 B2 B3 A0 A2 A1 A3
    STAGE(0, 0, 1, 0); STAGE(0, 0, 1, 1); STAGE(0, 0, 1, 2); STAGE(0, 0, 1, 3);
    STAGE(0, 0, 0, 0); STAGE(0, 0, 0, 2); STAGE(0, 0, 0, 1); STAGE(0, 0, 0, 3);
    asm volatile("s_waitcnt vmcnt(2)" ::: "memory");   // B*, A0, A2 landed
    __builtin_amdgcn_sched_barrier(0);
    __builtin_amdgcn_s_barrier();

    s16x8 bfrag[4][2];

    for (int kt = 0; kt < NT; ++kt) {
        const int d = kt & 1;
        const char* LA = (const char*)lbase + d * 65536;
        const char* LB = LA + 32768;
        const int nx = d ^ 1;
        const bool hn = (kt + 1 < NT);

        // ---- phase 0 (q=0): read all B + A-q0; stage next B0,B1
        {
            s16x8 a00, a01, a10, a11;
#pragma unroll
            for (int nj = 0; nj < 4; ++nj) {
                bfrag[nj][0] = *(const s16x8*)(LB + boff[nj][0]);
                bfrag[nj][1] = *(const s16x8*)(LB + boff[nj][1]);
            }
            a00 = *(const s16x8*)(LA + ar0 + ac0);
            a01 = *(const s16x8*)(LA + ar0 + ac1);
            a10 = *(const s16x8*)(LA + ar1 + ac0);
            a11 = *(const s16x8*)(LA + ar1 + ac1);
            if (hn) { STAGE(kt + 1, nx, 1, 0); STAGE(kt + 1, nx, 1, 1); }
            __builtin_amdgcn_s_barrier();
            __builtin_amdgcn_s_setprio(1);
#pragma unroll
            for (int nj = 0; nj < 4; ++nj) {
                acc[0][nj] = MFMA(a00, bfrag[nj][0], acc[0][nj], 0, 0, 0);
                acc[0][nj] = MFMA(a01, bfrag[nj][1], acc[0][nj], 0, 0, 0);
                acc[1][nj] = MFMA(a10, bfrag[nj][0], acc[1][nj], 0, 0, 0);
                acc[1][nj] = MFMA(a11, bfrag[nj][1], acc[1][nj], 0, 0, 0);
            }
            __builtin_amdgcn_s_setprio(0);
            __builtin_amdgcn_s_barrier();
        }
        // ---- phase 1 (q=1): A-q1; stage next B2,B3; W1
        {
            s16x8 a00 = *(const s16x8*)(LA + 4096 + ar0 + ac0);
            s16x8 a01 = *(const s16x8*)(LA + 4096 + ar0 + ac1);
            s16x8 a10 = *(const s16x8*)(LA + 4096 + ar1 + ac0);
            s16x8 a11 = *(const s16x8*)(LA + 4096 + ar1 + ac1);
            if (hn) { STAGE(kt + 1, nx, 1, 2); STAGE(kt + 1, nx, 1, 3); }
            __builtin_amdgcn_s_barrier();
            __builtin_amdgcn_s_setprio(1);
#pragma unroll
            for (int nj = 0; nj < 4; ++nj) {
                acc[2][nj] = MFMA(a00, bfrag[nj][0], acc[2][nj], 0, 0, 0);
                acc[2][nj] = MFMA(a01, bfrag[nj][1], acc[2][nj], 0, 0, 0);
                acc[3][nj] = MFMA(a10, bfrag[nj][0], acc[3][nj], 0, 0, 0);
                acc[3][nj] = MFMA(a11, bfrag[nj][1], acc[3][nj], 0, 0, 0);
            }
            __builtin_amdgcn_s_setprio(0);
            // W1: this tile's A1,A3 must be in LDS before phase-2 reads.
            if (hn) { asm volatile("s_waitcnt vmcnt(4)" ::: "memory"); }
            else    { asm volatile("s_waitcnt vmcnt(0)" ::: "memory"); }
            __builtin_amdgcn_sched_barrier(0);
            __builtin_amdgcn_s_barrier();
        }
        // ---- phase 2 (q=2): A-q2; stage next A0,A2
        {
            s16x8 a00 = *(const s16x8*)(LA + 8192 + ar0 + ac0);
            s16x8 a01 = *(const s16x8*)(LA + 8192 + ar0 + ac1);
            s16x8 a10 = *(const s16x8*)(LA + 8192 + ar1 + ac0);
            s16x8 a11 = *(const s16x8*)(LA + 8192 + ar1 + ac1);
            if (hn) { STAGE(kt + 1, nx, 0, 0); STAGE(kt + 1, nx, 0, 2); }
            __builtin_amdgcn_s_barrier();
            __builtin_amdgcn_s_setprio(1);
#pragma unroll
            for (int nj = 0; nj < 4; ++nj) {
                acc[4][nj] = MFMA(a00, bfrag[nj][0], acc[4][nj], 0, 0, 0);
                acc[4][nj] = MFMA(a01, bfrag[nj][1], acc[4][nj], 0, 0, 0);
                acc[5][nj] = MFMA(a10, bfrag[nj][0], acc[5][nj], 0, 0, 0);
                acc[5][nj] = MFMA(a11, bfrag[nj][1], acc[5][nj], 0, 0, 0);
            }
            __builtin_amdgcn_s_setprio(0);
            __builtin_amdgcn_s_barrier();
        }
        // ---- phase 3 (q=3): A-q3; stage next A1,A3; W2
        {
            s16x8 a00 = *(const s16x8*)(LA + 12288 + ar0 + ac0);
            s16x8 a01 = *(const s16x8*)(LA + 12288 + ar0 + ac1);
            s16x8 a10 = *(const s16x8*)(LA + 12288 + ar1 + ac0);
            s16x8 a11 = *(const s16x8*)(LA + 12288 + ar1 + ac1);
            if (hn) { STAGE(kt + 1, nx, 0, 1); STAGE(kt + 1, nx, 0, 3); }
            __builtin_amdgcn_s_barrier();
            __builtin_amdgcn_s_setprio(1);
#pragma unroll
            for (int nj = 0; nj < 4; ++nj) {
                acc[6][nj] = MFMA(a00, bfrag[nj][0], acc[6][nj], 0, 0, 0);
                acc[6][nj] = MFMA(a01, bfrag[nj][1], acc[6][nj], 0, 0, 0);
                acc[7][nj] = MFMA(a10, bfrag[nj][0], acc[7][nj], 0, 0, 0);
                acc[7][nj] = MFMA(a11, bfrag[nj][1], acc[7][nj], 0, 0, 0);
            }
            __builtin_amdgcn_s_setprio(0);
            // W2: next tile's B*,A0,A2 landed before its phase-0 reads.
            if (hn) {
                asm volatile("s_waitcnt vmcnt(2)" ::: "memory");
                __builtin_amdgcn_sched_barrier(0);
            }
            __builtin_amdgcn_s_barrier();
        }
    }

    // epilogue
    const float* biasp = bias + (size_t)bz * sbE;
#pragma unroll
    for (int mi = 0; mi < 8; ++mi) {
        const int rowb = m0 + wm * 128 + mi * 16 + hi * 4;
#pragma unroll
        for (int nj = 0; nj < 4; ++nj) {
            const int col = n0 + wn * 64 + nj * 16 + fr;
            const float bv = biasp[col];
#pragma unroll
            for (int r = 0; r < 4; ++r) {
                const int row = rowb + r;
                const size_t idx = (size_t)row * N + col;
                if (MODE == 0) {
                    ((u16*)Zv)[(size_t)bz * sZe + idx] = f2b(acc[mi][nj][r] + bv);
                } else if (MODE == 1) {
                    const float c = st[idx] + acc[mi][nj][r] + bv;
                    ((float*)Zv)[(size_t)bz * sZe + idx] = c;
                } else {
                    const float c = st[idx] + acc[mi][nj][r] + bv;
                    sum_o[idx] += c;
                    sq_o[idx] += c * c;
                }
            }
        }
    }
}

// ---------------- LayerNorm + exact GELU (+residual), wave-per-row ----------
__global__ __launch_bounds__(256) void k_ln(
    const u16* __restrict__ z, u16* __restrict__ h,
    const float* __restrict__ g, const float* __restrict__ be,
    int egb, int residual)
{
    const int lane = threadIdx.x & 63;
    const int w = threadIdx.x >> 6;
    const int e = blockIdx.z;
    const int row = blockIdx.x * 4 + w;
    const size_t base = ((size_t)e * B_SZ + row) * H_DIM;
    const u16* zr = z + base;
    u16* hr = h + base;
    const float* gp = g + (size_t)e * egb;
    const float* bp = be + (size_t)e * egb;

    float v[32];
    float s = 0.f, q = 0.f;
#pragma unroll
    for (int j = 0; j < 4; ++j) {
        u16x8 zv = *(const u16x8*)&zr[j * 512 + lane * 8];
#pragma unroll
        for (int k = 0; k < 8; ++k) {
            float f = b2f(zv[k]); v[j * 8 + k] = f; s += f; q += f * f;
        }
    }
#pragma unroll
    for (int o = 32; o; o >>= 1) { s += __shfl_xor(s, o); q += __shfl_xor(q, o); }
    const float mu = s * (1.0f / H_DIM);
    const float rsg = rsqrtf(q * (1.0f / H_DIM) - mu * mu + 1e-5f);
#pragma unroll
    for (int j = 0; j < 4; ++j) {
        const int c = j * 512 + lane * 8;
        u16x8 hv;
        if (residual) hv = *(const u16x8*)&hr[c];
        u16x8 ov;
#pragma unroll
        for (int k = 0; k < 8; ++k) {
            const float y = (v[j * 8 + k] - mu) * rsg * gp[c + k] + bp[c + k];
            float ge = 0.5f * y * (1.0f + erff(y * 0.70710678118f));
            if (residual) ge += b2f(hv[k]);
            ov[k] = f2b(ge);
        }
        *(u16x8*)&hr[c] = ov;
    }
}

// ---------------- reward/done heads: wave per batch row, atomics over e ------
__global__ __launch_bounds__(256) void k_rewdone(
    const u16* __restrict__ hB, const float* __restrict__ Wr, const float* __restrict__ Wd,
    const float* __restrict__ br, const float* __restrict__ bd,
    float* __restrict__ sum_rew, float* __restrict__ sum_done)
{
    const int e = blockIdx.z;
    const int lane = threadIdx.x & 63;
    const int b = blockIdx.x * 4 + (threadIdx.x >> 6);
    const u16* hrow = hB + ((size_t)e * B_SZ + b) * H_DIM;
    const float* wr_ = Wr + (size_t)e * H_DIM;
    const float* wd_ = Wd + (size_t)e * H_DIM;
    float dr = 0.f, dd = 0.f;
#pragma unroll
    for (int j = 0; j < 4; ++j) {
        const int o = j * 512 + lane * 8;
        u16x8 hv = *(const u16x8*)&hrow[o];
#pragma unroll
        for (int k = 0; k < 8; ++k) {
            const float f = b2f(hv[k]);
            dr += f * wr_[o + k];
            dd += f * wd_[o + k];
        }
    }
#pragma unroll
    for (int o = 32; o; o >>= 1) { dr += __shfl_xor(dr, o); dd += __shfl_xor(dd, o); }
    if (lane == 0) {
        atomicAdd(&sum_rew[b], dr + br[e]);
        atomicAdd(&sum_done[b], 1.0f / (1.0f + expf(-(dd + bd[e]))));
    }
}

// ---------------- finalize: mean/var over E ---------------------------------
template<int FB>
__global__ __launch_bounds__(256) void k_final(
    const float* __restrict__ P, const float* __restrict__ sum_st,
    const float* __restrict__ sq_st, const float* __restrict__ sum_rew,
    const float* __restrict__ sum_done, float* __restrict__ out)
{
    const int b = blockIdx.x, t = threadIdx.x;
    float vs = 0.f;
#pragma unroll
    for (int k = 0; k < 2; ++k) {
        const int s = t + k * 256;
        const size_t i = (size_t)b * S_DIM + s;
        float S1, S2;
        if (FB == 0) {
            S1 = 0.f; S2 = 0.f;
#pragma unroll
            for (int e = 0; e < 8; ++e) {
                const float c = P[(size_t)e * OUT_MS + i];
                S1 += c; S2 += c * c;
            }
        } else { S1 = sum_st[i]; S2 = sq_st[i]; }
        out[i] = S1 * 0.125f;
        vs += (S2 - S1 * S1 * 0.125f) * (1.0f / 7.0f);
    }
#pragma unroll
    for (int o = 32; o; o >>= 1) vs += __shfl_xor(vs, o);
    __shared__ float rv[4];
    if ((t & 63) == 0) rv[t >> 6] = vs;
    __syncthreads();
    if (t == 0) {
        const float tot = rv[0] + rv[1] + rv[2] + rv[3];
        out[OUT_MS + b] = sum_rew[b] * 0.125f;
        out[OUT_MS + B_SZ + b] = sum_done[b] * 0.125f;
        out[OUT_MS + 2 * B_SZ + b] = tot * (1.0f / S_DIM);
    }
}

extern "C" void kernel_launch(void* const* d_in, const int* in_sizes, int n_in,
                              void* d_out, int out_size, void* d_ws, size_t ws_size,
                              hipStream_t stream) {
    (void)in_sizes; (void)n_in; (void)out_size;
    const float* state   = (const float*)d_in[0];
    const float* action  = (const float*)d_in[1];
    const float* W_in    = (const float*)d_in[2];
    const float* b_in    = (const float*)d_in[3];
    const float* g_in    = (const float*)d_in[4];
    const float* be_in   = (const float*)d_in[5];
    const float* W_h     = (const float*)d_in[6];
    const float* b_h     = (const float*)d_in[7];
    const float* g_h     = (const float*)d_in[8];
    const float* be_h    = (const float*)d_in[9];
    const float* W_state = (const float*)d_in[10];
    const float* b_state = (const float*)d_in[11];
    const float* b_rew   = (const float*)d_in[13];
    const float* W_rew   = (const float*)d_in[12];
    const float* W_done  = (const float*)d_in[14];
    const float* b_done  = (const float*)d_in[15];
    float* out = (float*)d_out;

    char* ws = (char*)d_ws;
    size_t off = 0;
    auto alloc = [&](size_t bytes) -> void* {
        void* p = ws + off; off += (bytes + 255) & ~((size_t)255); return p;
    };
    const size_t BH = (size_t)B_SZ * H_DIM;       // 16777216
    u16*   xb      = (u16*)alloc((size_t)B_SZ * KIN * 2);
    u16*   Wt_in   = (u16*)alloc((size_t)8 * H_DIM * KIN * 2);
    u16*   Wt_h    = (u16*)alloc((size_t)24 * H_DIM * H_DIM * 2);
    u16*   Wt_st   = (u16*)alloc((size_t)8 * S_DIM * H_DIM * 2);
    float* sum_st  = (float*)alloc((size_t)B_SZ * S_DIM * 4);
    float* sq_st   = (float*)alloc((size_t)B_SZ * S_DIM * 4);
    float* sum_rew = (float*)alloc((size_t)B_SZ * 4);
    float* sum_done= (float*)alloc((size_t)B_SZ * 4);
    const size_t fixed = off;
    const int EB = (ws_size >= fixed + 2ULL * 8 * BH * 2) ? 8 : 1;
    u16*   hbuf    = (u16*)alloc((size_t)EB * BH * 2);
    u16*   zbuf    = (u16*)alloc((size_t)EB * BH * 2);
    float* Pbuf    = (float*)zbuf;   // batched: f32 next_states alias (dead zbuf)

    if (EB == 8) {
        hipMemsetAsync(sum_rew, 0, 2 * (size_t)B_SZ * 4, stream);
    } else {
        hipMemsetAsync(sum_st, 0, (2 * (size_t)B_SZ * S_DIM + 2 * B_SZ) * 4, stream);
    }

    k_concat<<<dim3((B_SZ * KIN) / 256), dim3(256), 0, stream>>>(state, action, xb);
    k_transpose<<<dim3(H_DIM / 32, KIN / 32, 8),    dim3(32, 8), 0, stream>>>(W_in, Wt_in, KIN, H_DIM);
    k_transpose<<<dim3(H_DIM / 32, H_DIM / 32, 24), dim3(32, 8), 0, stream>>>(W_h, Wt_h, H_DIM, H_DIM);
    k_transpose<<<dim3(S_DIM / 32, H_DIM / 32, 8),  dim3(32, 8), 0, stream>>>(W_state, Wt_st, H_DIM, S_DIM);

    for (int e0 = 0; e0 < 8; e0 += EB) {
        const dim3 gH(32, 8, EB), gS(32, 2, EB), gL(2048, 1, EB);
        k_gemm256<0><<<gH, 512, 0, stream>>>(
            xb, 0, Wt_in + (size_t)e0 * H_DIM * KIN, (size_t)H_DIM * KIN,
            b_in + (size_t)e0 * H_DIM, H_DIM, zbuf, BH,
            nullptr, nullptr, nullptr, H_DIM, KIN);
        k_ln<<<gL, 256, 0, stream>>>(zbuf, hbuf,
            g_in + (size_t)e0 * H_DIM, be_in + (size_t)e0 * H_DIM, H_DIM, 0);
        for (int l = 0; l < 3; ++l) {
            k_gemm256<0><<<gH, 512, 0, stream>>>(
                hbuf, BH, Wt_h + ((size_t)e0 * 3 + l) * H_DIM * H_DIM, (size_t)3 * H_DIM * H_DIM,
                b_h + (size_t)(e0 * 3 + l) * H_DIM, 3 * H_DIM, zbuf, BH,
                nullptr, nullptr, nullptr, H_DIM, H_DIM);
            k_ln<<<gL, 256, 0, stream>>>(zbuf, hbuf,
                g_h + (size_t)(e0 * 3 + l) * H_DIM, be_h + (size_t)(e0 * 3 + l) * H_DIM,
                3 * H_DIM, 1);
        }
        if (EB == 8) {
            k_gemm256<1><<<gS, 512, 0, stream>>>(
                hbuf, BH, Wt_st, (size_t)S_DIM * H_DIM,
                b_state, S_DIM, (void*)Pbuf, (size_t)OUT_MS,
                state, nullptr, nullptr, S_DIM, H_DIM);
        } else {
            k_gemm256<2><<<gS, 512, 0, stream>>>(
                hbuf, BH, Wt_st + (size_t)e0 * S_DIM * H_DIM, (size_t)S_DIM * H_DIM,
                b_state + (size_t)e0 * S_DIM, S_DIM, (void*)zbuf, 0,
                state, sum_st, sq_st, S_DIM, H_DIM);
        }
        k_rewdone<<<gL, 256, 0, stream>>>(hbuf,
            W_rew + (size_t)e0 * H_DIM, W_done + (size_t)e0 * H_DIM,
            b_rew + e0, b_done + e0, sum_rew, sum_done);
    }
    if (EB == 8)
        k_final<0><<<dim3(B_SZ), dim3(256), 0, stream>>>(Pbuf, nullptr, nullptr, sum_rew, sum_done, out);
    else
        k_final<1><<<dim3(B_SZ), dim3(256), 0, stream>>>(nullptr, sum_st, sq_st, sum_rew, sum_done, out);
}

// Round 4
// 3973.879 us; speedup vs baseline: 1.5284x; 1.0213x over previous
//
#include <hip/hip_runtime.h>
#include <stdint.h>

#define B_SZ  8192
#define S_DIM 512
#define H_DIM 2048
#define KIN   576
#define OUT_MS 4194304  // B*S

typedef unsigned short u16;
typedef u16   u16x8 __attribute__((ext_vector_type(8)));
typedef short s16x8 __attribute__((ext_vector_type(8)));
typedef float f32x4 __attribute__((ext_vector_type(4)));

__device__ __forceinline__ float b2f(u16 u) {
    union { unsigned int i; float f; } v; v.i = ((unsigned int)u) << 16; return v.f;
}
__device__ __forceinline__ u16 f2b(float f) {
    union { float f; unsigned int i; } v; v.f = f;
    unsigned int u = v.i;
    return (u16)((u + 0x7FFFu + ((u >> 16) & 1u)) >> 16);  // RNE
}

__device__ __forceinline__ void gload_lds16(const void* gp, void* lp) {
    __builtin_amdgcn_global_load_lds(
        (const __attribute__((address_space(1))) unsigned int*)gp,
        (__attribute__((address_space(3))) unsigned int*)(unsigned int)(uintptr_t)lp,
        16, 0, 0);
}

#define MFMA __builtin_amdgcn_mfma_f32_16x16x32_bf16

// ---------------- concat + cast to bf16 ------------------------------------
__global__ __launch_bounds__(256) void k_concat(
    const float* __restrict__ state, const float* __restrict__ action,
    u16* __restrict__ xb)
{
    int idx = blockIdx.x * 256 + threadIdx.x;
    int b = idx / KIN, c = idx - b * KIN;
    float v = (c < S_DIM) ? state[(size_t)b * S_DIM + c]
                          : action[(size_t)b * 64 + (c - S_DIM)];
    xb[idx] = f2b(v);
}

// ---------------- f32 [R][C] -> bf16 [C][R] (per-z matrix) -------------------
__global__ __launch_bounds__(256) void k_transpose(
    const float* __restrict__ src, u16* __restrict__ dst, int R, int C)
{
    __shared__ float tile[32][33];
    const int tx = threadIdx.x, ty = threadIdx.y;
    const int c0 = blockIdx.x * 32, r0 = blockIdx.y * 32;
    const size_t mo = (size_t)blockIdx.z * R * C;
    src += mo; dst += mo;
#pragma unroll
    for (int j = 0; j < 4; ++j)
        tile[ty + j * 8][tx] = src[(size_t)(r0 + ty + j * 8) * C + c0 + tx];
    __syncthreads();
#pragma unroll
    for (int j = 0; j < 4; ++j)
        dst[(size_t)(c0 + ty + j * 8) * R + r0 + tx] = f2b(tile[tx][ty + j * 8]);
}

// ---------------- 256x256 GEMM, m201-faithful 8-phase/2-K-tile schedule ------
// C[M,N] = A[M,K](bf16) * Bt[N,K](bf16)^T ; 512 thr = 8 waves (2M x 4N),
// BK=64, LDS 128KiB (buf d = tile parity), st-swizzle both sides,
// per-iteration (2 K-tiles, 8 phases) staging stagger:
//  ph0: A(t1)r1r3 | ph1: B(t0')r0r1 | ph2: B(t0')r2r3 | ph3: A(t0')r0r2 +vmcnt(6)
//  ph4: A(t0')r1r3 | ph5: B(t1')r0r1 | ph6: B(t1')r2r3 | ph7: A(t1')r0r2 +vmcnt(6)
// Each staged region was last read one-or-more phases before its issue.
// MODE 0: Z(u16) = bf16(acc+bias); MODE 1: P(f32) = state+acc+bias;
// MODE 2: c = state+acc+bias; sum_o += c; sq_o += c*c (non-atomic, seq e)
template<int MODE>
__global__ __launch_bounds__(512, 2) void k_gemm256(
    const u16* __restrict__ A, size_t sAe,
    const u16* __restrict__ Bt, size_t sBe,
    const float* __restrict__ bias, int sbE,
    void* __restrict__ Zv, size_t sZe,
    const float* __restrict__ st, float* __restrict__ sum_o, float* __restrict__ sq_o,
    int N, int K)
{
    __shared__ __align__(16) u16 lds[2][32768];   // [tile parity][A 32KB | B 32KB]
    const int t = threadIdx.x;
    const int lane = t & 63;
    const int wid = t >> 6;
    const int wm = wid >> 2, wn = wid & 3;

    // locality swizzle: e-major, per-XCD contiguous bx, by fastest (gx % 8 == 0)
    const int gx = gridDim.x, gy = gridDim.y;
    const int linb = blockIdx.x + gx * (blockIdx.y + gy * blockIdx.z);
    const int x  = linb & 7;
    const int s  = linb >> 3;
    const int m_ = (gx * gy) >> 3;
    const int bz = s / m_;
    const int r_ = s - bz * m_;
    const int p_ = r_ / gy;
    const int by = r_ - p_ * gy;
    const int bx = x * (gx >> 3) + p_;
    const int m0 = bx * 256, n0 = by * 256;

    const u16* Ab = A + (size_t)bz * sAe + (size_t)m0 * K;
    const u16* Bb = Bt + (size_t)bz * sBe + (size_t)n0 * K;

    // staging: one load = 64 rows x 64 cols, thread covers 16B, src pre-swizzled
    const int srow = t >> 3;
    const int scol = (((t & 7) ^ (srow & 7)) * 8);
    const u16* gA = Ab + (size_t)srow * K + scol;
    const u16* gB = Bb + (size_t)srow * K + scol;
    u16* lbase = &lds[0][0];
    const int ldst = srow * 64 + (t & 7) * 8;
    const int NT = K >> 6;
    const int NT2 = NT >> 1;

    auto STAGE = [&](int kt, int mat, int r) {
        const u16* gp = (mat ? gB : gA) + (size_t)(r * 64) * K + kt * 64;
        u16* lp = lbase + (kt & 1) * 32768 + mat * 16384 + r * 4096 + ldst;
        gload_lds16(gp, lp);
    };

    // fragment LDS byte offsets (within matrix slab), swizzled reads
    const int fr = lane & 15, hi = lane >> 4;
    const int cswz = (fr & 7) << 4;
    const int ac0 = (hi * 16) ^ cswz;              // k-half 0
    const int ac1 = (64 + hi * 16) ^ cswz;         // k-half 1
    const int ar0 = (wm * 128 + fr) * 128;
    const int ar1 = (wm * 128 + 16 + fr) * 128;
    int boff[4][2];
#pragma unroll
    for (int nj = 0; nj < 4; ++nj) {
        const int br_ = (wn * 64 + nj * 16 + fr) * 128;
        boff[nj][0] = br_ + ac0;
        boff[nj][1] = br_ + ac1;
    }

    f32x4 acc[8][4];
#pragma unroll
    for (int i = 0; i < 8; ++i)
#pragma unroll
        for (int j = 0; j < 4; ++j) acc[i][j] = (f32x4){0.f, 0.f, 0.f, 0.f};

    s16x8 bfrag[4][2];
    s16x8 af[4];

    const char* LA0 = (const char*)lbase;
    const char* LB0 = LA0 + 32768;
    const char* LA1 = LA0 + 65536;
    const char* LB1 = LA1 + 32768;

#define LOADB(LBx)                                                        \
    _Pragma("unroll") for (int nj = 0; nj < 4; ++nj) {                    \
        bfrag[nj][0] = *(const s16x8*)((LBx) + boff[nj][0]);              \
        bfrag[nj][1] = *(const s16x8*)((LBx) + boff[nj][1]);              \
    }
#define LOADA(LAx, Q)                                                     \
    af[0] = *(const s16x8*)((LAx) + (Q) * 4096 + ar0 + ac0);              \
    af[1] = *(const s16x8*)((LAx) + (Q) * 4096 + ar0 + ac1);              \
    af[2] = *(const s16x8*)((LAx) + (Q) * 4096 + ar1 + ac0);              \
    af[3] = *(const s16x8*)((LAx) + (Q) * 4096 + ar1 + ac1);
#define DOMFMA(Q)                                                         \
    __builtin_amdgcn_s_barrier();                                         \
    __builtin_amdgcn_s_setprio(1);                                        \
    _Pragma("unroll") for (int nj = 0; nj < 4; ++nj) {                    \
        acc[2*(Q)][nj]   = MFMA(af[0], bfrag[nj][0], acc[2*(Q)][nj], 0, 0, 0);   \
        acc[2*(Q)][nj]   = MFMA(af[1], bfrag[nj][1], acc[2*(Q)][nj], 0, 0, 0);   \
        acc[2*(Q)+1][nj] = MFMA(af[2], bfrag[nj][0], acc[2*(Q)+1][nj], 0, 0, 0); \
        acc[2*(Q)+1][nj] = MFMA(af[3], bfrag[nj][1], acc[2*(Q)+1][nj], 0, 0, 0); \
    }                                                                     \
    __builtin_amdgcn_s_setprio(0);
#define WAITV(COND)                                                       \
    if (COND) { asm volatile("s_waitcnt vmcnt(6)" ::: "memory"); }        \
    else      { asm volatile("s_waitcnt vmcnt(0)" ::: "memory"); }        \
    __builtin_amdgcn_sched_barrier(0);

    // prologue: tile0 complete (8 loads), tile1 partial (B all + A r0,r2)
    STAGE(0, 1, 0); STAGE(0, 1, 1); STAGE(0, 1, 2); STAGE(0, 1, 3);
    STAGE(0, 0, 0); STAGE(0, 0, 2); STAGE(0, 0, 1); STAGE(0, 0, 3);
    STAGE(1, 1, 0); STAGE(1, 1, 1); STAGE(1, 1, 2); STAGE(1, 1, 3);
    STAGE(1, 0, 0); STAGE(1, 0, 2);
    asm volatile("s_waitcnt vmcnt(6)" ::: "memory");   // tile0 fully landed
    __builtin_amdgcn_sched_barrier(0);
    __builtin_amdgcn_s_barrier();

    for (int i2 = 0; i2 < NT2; ++i2) {
        const int t1 = 2 * i2 + 1, tn0 = t1 + 1, tn1 = t1 + 2;
        const bool h0 = tn0 < NT, h1 = tn1 < NT;
        // ph0: B(t0)+A q0 from buf0; finish staging A(t1) r1,r3
        LOADB(LB0) LOADA(LA0, 0)
        STAGE(t1, 0, 1); STAGE(t1, 0, 3);
        DOMFMA(0)
        __builtin_amdgcn_s_barrier();
        // ph1
        LOADA(LA0, 1)
        if (h0) { STAGE(tn0, 1, 0); STAGE(tn0, 1, 1); }
        DOMFMA(1)
        __builtin_amdgcn_s_barrier();
        // ph2
        LOADA(LA0, 2)
        if (h0) { STAGE(tn0, 1, 2); STAGE(tn0, 1, 3); }
        DOMFMA(2)
        __builtin_amdgcn_s_barrier();
        // ph3  (wait: tile t1 fully landed)
        LOADA(LA0, 3)
        if (h0) { STAGE(tn0, 0, 0); STAGE(tn0, 0, 2); }
        DOMFMA(3)
        WAITV(h0)
        __builtin_amdgcn_s_barrier();
        // ph4: B(t1)+A q0 from buf1
        LOADB(LB1) LOADA(LA1, 0)
        if (h0) { STAGE(tn0, 0, 1); STAGE(tn0, 0, 3); }
        DOMFMA(0)
        __builtin_amdgcn_s_barrier();
        // ph5
        LOADA(LA1, 1)
        if (h1) { STAGE(tn1, 1, 0); STAGE(tn1, 1, 1); }
        DOMFMA(1)
        __builtin_amdgcn_s_barrier();
        // ph6
        LOADA(LA1, 2)
        if (h1) { STAGE(tn1, 1, 2); STAGE(tn1, 1, 3); }
        DOMFMA(2)
        __builtin_amdgcn_s_barrier();
        // ph7  (wait: tile tn0 fully landed)
        LOADA(LA1, 3)
        if (h1) { STAGE(tn1, 0, 0); STAGE(tn1, 0, 2); }
        DOMFMA(3)
        WAITV(h1)
        __builtin_amdgcn_s_barrier();
    }
    if (NT & 1) {   // tail tile NT-1 (even parity -> buf0), fully staged+drained
        LOADB(LB0) LOADA(LA0, 0) DOMFMA(0)
        __builtin_amdgcn_s_barrier();
        LOADA(LA0, 1) DOMFMA(1)
        __builtin_amdgcn_s_barrier();
        LOADA(LA0, 2) DOMFMA(2)
        __builtin_amdgcn_s_barrier();
        LOADA(LA0, 3) DOMFMA(3)
    }
#undef LOADB
#undef LOADA
#undef DOMFMA
#undef WAITV

    // epilogue
    const float* biasp = bias + (size_t)bz * sbE;
#pragma unroll
    for (int mi = 0; mi < 8; ++mi) {
        const int rowb = m0 + wm * 128 + mi * 16 + hi * 4;
#pragma unroll
        for (int nj = 0; nj < 4; ++nj) {
            const int col = n0 + wn * 64 + nj * 16 + fr;
            const float bv = biasp[col];
#pragma unroll
            for (int r = 0; r < 4; ++r) {
                const int row = rowb + r;
                const size_t idx = (size_t)row * N + col;
                if (MODE == 0) {
                    ((u16*)Zv)[(size_t)bz * sZe + idx] = f2b(acc[mi][nj][r] + bv);
                } else if (MODE == 1) {
                    const float c = st[idx] + acc[mi][nj][r] + bv;
                    ((float*)Zv)[(size_t)bz * sZe + idx] = c;
                } else {
                    const float c = st[idx] + acc[mi][nj][r] + bv;
                    sum_o[idx] += c;
                    sq_o[idx] += c * c;
                }
            }
        }
    }
}

// ---------------- LayerNorm + exact GELU (+residual), wave-per-row ----------
__global__ __launch_bounds__(256) void k_ln(
    const u16* __restrict__ z, u16* __restrict__ h,
    const float* __restrict__ g, const float* __restrict__ be,
    int egb, int residual)
{
    const int lane = threadIdx.x & 63;
    const int w = threadIdx.x >> 6;
    const int e = blockIdx.z;
    const int row = blockIdx.x * 4 + w;
    const size_t base = ((size_t)e * B_SZ + row) * H_DIM;
    const u16* zr = z + base;
    u16* hr = h + base;
    const float* gp = g + (size_t)e * egb;
    const float* bp = be + (size_t)e * egb;

    float v[32];
    float s = 0.f, q = 0.f;
#pragma unroll
    for (int j = 0; j < 4; ++j) {
        u16x8 zv = *(const u16x8*)&zr[j * 512 + lane * 8];
#pragma unroll
        for (int k = 0; k < 8; ++k) {
            float f = b2f(zv[k]); v[j * 8 + k] = f; s += f; q += f * f;
        }
    }
#pragma unroll
    for (int o = 32; o; o >>= 1) { s += __shfl_xor(s, o); q += __shfl_xor(q, o); }
    const float mu = s * (1.0f / H_DIM);
    const float rsg = rsqrtf(q * (1.0f / H_DIM) - mu * mu + 1e-5f);
#pragma unroll
    for (int j = 0; j < 4; ++j) {
        const int c = j * 512 + lane * 8;
        u16x8 hv;
        if (residual) hv = *(const u16x8*)&hr[c];
        u16x8 ov;
#pragma unroll
        for (int k = 0; k < 8; ++k) {
            const float y = (v[j * 8 + k] - mu) * rsg * gp[c + k] + bp[c + k];
            float ge = 0.5f * y * (1.0f + erff(y * 0.70710678118f));
            if (residual) ge += b2f(hv[k]);
            ov[k] = f2b(ge);
        }
        *(u16x8*)&hr[c] = ov;
    }
}

// ---------------- reward/done heads: wave per batch row, atomics over e ------
__global__ __launch_bounds__(256) void k_rewdone(
    const u16* __restrict__ hB, const float* __restrict__ Wr, const float* __restrict__ Wd,
    const float* __restrict__ br, const float* __restrict__ bd,
    float* __restrict__ sum_rew, float* __restrict__ sum_done)
{
    const int e = blockIdx.z;
    const int lane = threadIdx.x & 63;
    const int b = blockIdx.x * 4 + (threadIdx.x >> 6);
    const u16* hrow = hB + ((size_t)e * B_SZ + b) * H_DIM;
    const float* wr_ = Wr + (size_t)e * H_DIM;
    const float* wd_ = Wd + (size_t)e * H_DIM;
    float dr = 0.f, dd = 0.f;
#pragma unroll
    for (int j = 0; j < 4; ++j) {
        const int o = j * 512 + lane * 8;
        u16x8 hv = *(const u16x8*)&hrow[o];
#pragma unroll
        for (int k = 0; k < 8; ++k) {
            const float f = b2f(hv[k]);
            dr += f * wr_[o + k];
            dd += f * wd_[o + k];
        }
    }
#pragma unroll
    for (int o = 32; o; o >>= 1) { dr += __shfl_xor(dr, o); dd += __shfl_xor(dd, o); }
    if (lane == 0) {
        atomicAdd(&sum_rew[b], dr + br[e]);
        atomicAdd(&sum_done[b], 1.0f / (1.0f + expf(-(dd + bd[e]))));
    }
}

// ---------------- finalize: mean/var over E ---------------------------------
template<int FB>
__global__ __launch_bounds__(256) void k_final(
    const float* __restrict__ P, const float* __restrict__ sum_st,
    const float* __restrict__ sq_st, const float* __restrict__ sum_rew,
    const float* __restrict__ sum_done, float* __restrict__ out)
{
    const int b = blockIdx.x, t = threadIdx.x;
    float vs = 0.f;
#pragma unroll
    for (int k = 0; k < 2; ++k) {
        const int s = t + k * 256;
        const size_t i = (size_t)b * S_DIM + s;
        float S1, S2;
        if (FB == 0) {
            S1 = 0.f; S2 = 0.f;
#pragma unroll
            for (int e = 0; e < 8; ++e) {
                const float c = P[(size_t)e * OUT_MS + i];
                S1 += c; S2 += c * c;
            }
        } else { S1 = sum_st[i]; S2 = sq_st[i]; }
        out[i] = S1 * 0.125f;
        vs += (S2 - S1 * S1 * 0.125f) * (1.0f / 7.0f);
    }
#pragma unroll
    for (int o = 32; o; o >>= 1) vs += __shfl_xor(vs, o);
    __shared__ float rv[4];
    if ((t & 63) == 0) rv[t >> 6] = vs;
    __syncthreads();
    if (t == 0) {
        const float tot = rv[0] + rv[1] + rv[2] + rv[3];
        out[OUT_MS + b] = sum_rew[b] * 0.125f;
        out[OUT_MS + B_SZ + b] = sum_done[b] * 0.125f;
        out[OUT_MS + 2 * B_SZ + b] = tot * (1.0f / S_DIM);
    }
}

extern "C" void kernel_launch(void* const* d_in, const int* in_sizes, int n_in,
                              void* d_out, int out_size, void* d_ws, size_t ws_size,
                              hipStream_t stream) {
    (void)in_sizes; (void)n_in; (void)out_size;
    const float* state   = (const float*)d_in[0];
    const float* action  = (const float*)d_in[1];
    const float* W_in    = (const float*)d_in[2];
    const float* b_in    = (const float*)d_in[3];
    const float* g_in    = (const float*)d_in[4];
    const float* be_in   = (const float*)d_in[5];
    const float* W_h     = (const float*)d_in[6];
    const float* b_h     = (const float*)d_in[7];
    const float* g_h     = (const float*)d_in[8];
    const float* be_h    = (const float*)d_in[9];
    const float* W_state = (const float*)d_in[10];
    const float* b_state = (const float*)d_in[11];
    const float* b_rew   = (const float*)d_in[13];
    const float* W_rew   = (const float*)d_in[12];
    const float* W_done  = (const float*)d_in[14];
    const float* b_done  = (const float*)d_in[15];
    float* out = (float*)d_out;

    char* ws = (char*)d_ws;
    size_t off = 0;
    auto alloc = [&](size_t bytes) -> void* {
        void* p = ws + off; off += (bytes + 255) & ~((size_t)255); return p;
    };
    const size_t BH = (size_t)B_SZ * H_DIM;       // 16777216
    u16*   xb      = (u16*)alloc((size_t)B_SZ * KIN * 2);
    u16*   Wt_in   = (u16*)alloc((size_t)8 * H_DIM * KIN * 2);
    u16*   Wt_h    = (u16*)alloc((size_t)24 * H_DIM * H_DIM * 2);
    u16*   Wt_st   = (u16*)alloc((size_t)8 * S_DIM * H_DIM * 2);
    float* sum_st  = (float*)alloc((size_t)B_SZ * S_DIM * 4);
    float* sq_st   = (float*)alloc((size_t)B_SZ * S_DIM * 4);
    float* sum_rew = (float*)alloc((size_t)B_SZ * 4);
    float* sum_done= (float*)alloc((size_t)B_SZ * 4);
    const size_t fixed = off;
    const int EB = (ws_size >= fixed + 2ULL * 8 * BH * 2) ? 8 : 1;
    u16*   hbuf    = (u16*)alloc((size_t)EB * BH * 2);
    u16*   zbuf    = (u16*)alloc((size_t)EB * BH * 2);
    float* Pbuf    = (float*)zbuf;   // batched: f32 next_states alias (dead zbuf)

    if (EB == 8) {
        hipMemsetAsync(sum_rew, 0, 2 * (size_t)B_SZ * 4, stream);
    } else {
        hipMemsetAsync(sum_st, 0, (2 * (size_t)B_SZ * S_DIM + 2 * B_SZ) * 4, stream);
    }

    k_concat<<<dim3((B_SZ * KIN) / 256), dim3(256), 0, stream>>>(state, action, xb);
    k_transpose<<<dim3(H_DIM / 32, KIN / 32, 8),    dim3(32, 8), 0, stream>>>(W_in, Wt_in, KIN, H_DIM);
    k_transpose<<<dim3(H_DIM / 32, H_DIM / 32, 24), dim3(32, 8), 0, stream>>>(W_h, Wt_h, H_DIM, H_DIM);
    k_transpose<<<dim3(S_DIM / 32, H_DIM / 32, 8),  dim3(32, 8), 0, stream>>>(W_state, Wt_st, H_DIM, S_DIM);

    for (int e0 = 0; e0 < 8; e0 += EB) {
        const dim3 gH(32, 8, EB), gS(32, 2, EB), gL(2048, 1, EB);
        k_gemm256<0><<<gH, 512, 0, stream>>>(
            xb, 0, Wt_in + (size_t)e0 * H_DIM * KIN, (size_t)H_DIM * KIN,
            b_in + (size_t)e0 * H_DIM, H_DIM, zbuf, BH,
            nullptr, nullptr, nullptr, H_DIM, KIN);
        k_ln<<<gL, 256, 0, stream>>>(zbuf, hbuf,
            g_in + (size_t)e0 * H_DIM, be_in + (size_t)e0 * H_DIM, H_DIM, 0);
        for (int l = 0; l < 3; ++l) {
            k_gemm256<0><<<gH, 512, 0, stream>>>(
                hbuf, BH, Wt_h + ((size_t)e0 * 3 + l) * H_DIM * H_DIM, (size_t)3 * H_DIM * H_DIM,
                b_h + (size_t)(e0 * 3 + l) * H_DIM, 3 * H_DIM, zbuf, BH,
                nullptr, nullptr, nullptr, H_DIM, H_DIM);
            k_ln<<<gL, 256, 0, stream>>>(zbuf, hbuf,
                g_h + (size_t)(e0 * 3 + l) * H_DIM, be_h + (size_t)(e0 * 3 + l) * H_DIM,
                3 * H_DIM, 1);
        }
        if (EB == 8) {
            k_gemm256<1><<<gS, 512, 0, stream>>>(
                hbuf, BH, Wt_st, (size_t)S_DIM * H_DIM,
                b_state, S_DIM, (void*)Pbuf, (size_t)OUT_MS,
                state, nullptr, nullptr, S_DIM, H_DIM);
        } else {
            k_gemm256<2><<<gS, 512, 0, stream>>>(
                hbuf, BH, Wt_st + (size_t)e0 * S_DIM * H_DIM, (size_t)S_DIM * H_DIM,
                b_state + (size_t)e0 * S_DIM, S_DIM, (void*)zbuf, 0,
                state, sum_st, sq_st, S_DIM, H_DIM);
        }
        k_rewdone<<<gL, 256, 0, stream>>>(hbuf,
            W_rew + (size_t)e0 * H_DIM, W_done + (size_t)e0 * H_DIM,
            b_rew + e0, b_done + e0, sum_rew, sum_done);
    }
    if (EB == 8)
        k_final<0><<<dim3(B_SZ), dim3(256), 0, stream>>>(Pbuf, nullptr, nullptr, sum_rew, sum_done, out);
    else
        k_final<1><<<dim3(B_SZ), dim3(256), 0, stream>>>(nullptr, sum_st, sq_st, sum_rew, sum_done, out);
}

// Round 5
// 2578.814 us; speedup vs baseline: 2.3552x; 1.5410x over previous
//
#include <hip/hip_runtime.h>
#include <stdint.h>

#define B_SZ  8192
#define S_DIM 512
#define H_DIM 2048
#define KIN   576
#define OUT_MS 4194304  // B*S

typedef unsigned short u16;
typedef u16   u16x8 __attribute__((ext_vector_type(8)));
typedef short s16x8 __attribute__((ext_vector_type(8)));
typedef float f32x4 __attribute__((ext_vector_type(4)));

__device__ __forceinline__ float b2f(u16 u) {
    union { unsigned int i; float f; } v; v.i = ((unsigned int)u) << 16; return v.f;
}
__device__ __forceinline__ u16 f2b(float f) {
    union { float f; unsigned int i; } v; v.f = f;
    unsigned int u = v.i;
    return (u16)((u + 0x7FFFu + ((u >> 16) & 1u)) >> 16);  // RNE
}
// tanh-form GELU via sigmoid: y*sigma(1.59577*y*(1+0.044715*y^2)); |err|<=~1e-3
__device__ __forceinline__ float gelu_f(float y) {
    const float t = __expf(-1.5957691216f * y * (1.0f + 0.044715f * y * y));
    return y / (1.0f + t);
}

__device__ __forceinline__ void gload_lds16(const void* gp, void* lp) {
    __builtin_amdgcn_global_load_lds(
        (const __attribute__((address_space(1))) unsigned int*)gp,
        (__attribute__((address_space(3))) unsigned int*)(unsigned int)(uintptr_t)lp,
        16, 0, 0);
}

#define MFMA __builtin_amdgcn_mfma_f32_16x16x32_bf16

// ---------------- concat + cast to bf16 ------------------------------------
__global__ __launch_bounds__(256) void k_concat(
    const float* __restrict__ state, const float* __restrict__ action,
    u16* __restrict__ xb)
{
    int idx = blockIdx.x * 256 + threadIdx.x;
    int b = idx / KIN, c = idx - b * KIN;
    float v = (c < S_DIM) ? state[(size_t)b * S_DIM + c]
                          : action[(size_t)b * 64 + (c - S_DIM)];
    xb[idx] = f2b(v);
}

// ---------------- f32 -> bf16 cast of 6 param arrays into one ws buffer -----
__global__ __launch_bounds__(256) void k_cast(
    const float* __restrict__ p0, const float* __restrict__ p1,
    const float* __restrict__ p2, const float* __restrict__ p3,
    const float* __restrict__ p4, const float* __restrict__ p5,
    u16* __restrict__ dst)
{
    // layout: [g_in 16384][be_in 16384][g_h 49152][be_h 49152][wr 16384][wd 16384]
    int i = blockIdx.x * 256 + threadIdx.x;   // grid covers 163840
    float v;
    if      (i < 16384)  v = p0[i];
    else if (i < 32768)  v = p1[i - 16384];
    else if (i < 81920)  v = p2[i - 32768];
    else if (i < 131072) v = p3[i - 81920];
    else if (i < 147456) v = p4[i - 131072];
    else                 v = p5[i - 147456];
    dst[i] = f2b(v);
}

// ---------------- f32 [R][C] -> bf16 [C][R] (per-z matrix) -------------------
__global__ __launch_bounds__(256) void k_transpose(
    const float* __restrict__ src, u16* __restrict__ dst, int R, int C)
{
    __shared__ float tile[32][33];
    const int tx = threadIdx.x, ty = threadIdx.y;
    const int c0 = blockIdx.x * 32, r0 = blockIdx.y * 32;
    const size_t mo = (size_t)blockIdx.z * R * C;
    src += mo; dst += mo;
#pragma unroll
    for (int j = 0; j < 4; ++j)
        tile[ty + j * 8][tx] = src[(size_t)(r0 + ty + j * 8) * C + c0 + tx];
    __syncthreads();
#pragma unroll
    for (int j = 0; j < 4; ++j)
        dst[(size_t)(c0 + ty + j * 8) * R + r0 + tx] = f2b(tile[tx][ty + j * 8]);
}

// ---------------- 256x256 GEMM, 8-phase/2-K-tile schedule (unchanged R3) -----
template<int MODE>
__global__ __launch_bounds__(512, 2) void k_gemm256(
    const u16* __restrict__ A, size_t sAe,
    const u16* __restrict__ Bt, size_t sBe,
    const float* __restrict__ bias, int sbE,
    void* __restrict__ Zv, size_t sZe,
    const float* __restrict__ st, float* __restrict__ sum_o, float* __restrict__ sq_o,
    int N, int K)
{
    __shared__ __align__(16) u16 lds[2][32768];   // [tile parity][A 32KB | B 32KB]
    const int t = threadIdx.x;
    const int lane = t & 63;
    const int wid = t >> 6;
    const int wm = wid >> 2, wn = wid & 3;

    // locality swizzle: e-major, per-XCD contiguous bx, by fastest (gx % 8 == 0)
    const int gx = gridDim.x, gy = gridDim.y;
    const int linb = blockIdx.x + gx * (blockIdx.y + gy * blockIdx.z);
    const int x  = linb & 7;
    const int s  = linb >> 3;
    const int m_ = (gx * gy) >> 3;
    const int bz = s / m_;
    const int r_ = s - bz * m_;
    const int p_ = r_ / gy;
    const int by = r_ - p_ * gy;
    const int bx = x * (gx >> 3) + p_;
    const int m0 = bx * 256, n0 = by * 256;

    const u16* Ab = A + (size_t)bz * sAe + (size_t)m0 * K;
    const u16* Bb = Bt + (size_t)bz * sBe + (size_t)n0 * K;

    const int srow = t >> 3;
    const int scol = (((t & 7) ^ (srow & 7)) * 8);
    const u16* gA = Ab + (size_t)srow * K + scol;
    const u16* gB = Bb + (size_t)srow * K + scol;
    u16* lbase = &lds[0][0];
    const int ldst = srow * 64 + (t & 7) * 8;
    const int NT = K >> 6;
    const int NT2 = NT >> 1;

    auto STAGE = [&](int kt, int mat, int r) {
        const u16* gp = (mat ? gB : gA) + (size_t)(r * 64) * K + kt * 64;
        u16* lp = lbase + (kt & 1) * 32768 + mat * 16384 + r * 4096 + ldst;
        gload_lds16(gp, lp);
    };

    const int fr = lane & 15, hi = lane >> 4;
    const int cswz = (fr & 7) << 4;
    const int ac0 = (hi * 16) ^ cswz;
    const int ac1 = (64 + hi * 16) ^ cswz;
    const int ar0 = (wm * 128 + fr) * 128;
    const int ar1 = (wm * 128 + 16 + fr) * 128;
    int boff[4][2];
#pragma unroll
    for (int nj = 0; nj < 4; ++nj) {
        const int br_ = (wn * 64 + nj * 16 + fr) * 128;
        boff[nj][0] = br_ + ac0;
        boff[nj][1] = br_ + ac1;
    }

    f32x4 acc[8][4];
#pragma unroll
    for (int i = 0; i < 8; ++i)
#pragma unroll
        for (int j = 0; j < 4; ++j) acc[i][j] = (f32x4){0.f, 0.f, 0.f, 0.f};

    s16x8 bfrag[4][2];
    s16x8 af[4];

    const char* LA0 = (const char*)lbase;
    const char* LB0 = LA0 + 32768;
    const char* LA1 = LA0 + 65536;
    const char* LB1 = LA1 + 32768;

#define LOADB(LBx)                                                        \
    _Pragma("unroll") for (int nj = 0; nj < 4; ++nj) {                    \
        bfrag[nj][0] = *(const s16x8*)((LBx) + boff[nj][0]);              \
        bfrag[nj][1] = *(const s16x8*)((LBx) + boff[nj][1]);              \
    }
#define LOADA(LAx, Q)                                                     \
    af[0] = *(const s16x8*)((LAx) + (Q) * 4096 + ar0 + ac0);              \
    af[1] = *(const s16x8*)((LAx) + (Q) * 4096 + ar0 + ac1);              \
    af[2] = *(const s16x8*)((LAx) + (Q) * 4096 + ar1 + ac0);              \
    af[3] = *(const s16x8*)((LAx) + (Q) * 4096 + ar1 + ac1);
#define DOMFMA(Q)                                                         \
    __builtin_amdgcn_s_barrier();                                         \
    __builtin_amdgcn_s_setprio(1);                                        \
    _Pragma("unroll") for (int nj = 0; nj < 4; ++nj) {                    \
        acc[2*(Q)][nj]   = MFMA(af[0], bfrag[nj][0], acc[2*(Q)][nj], 0, 0, 0);   \
        acc[2*(Q)][nj]   = MFMA(af[1], bfrag[nj][1], acc[2*(Q)][nj], 0, 0, 0);   \
        acc[2*(Q)+1][nj] = MFMA(af[2], bfrag[nj][0], acc[2*(Q)+1][nj], 0, 0, 0); \
        acc[2*(Q)+1][nj] = MFMA(af[3], bfrag[nj][1], acc[2*(Q)+1][nj], 0, 0, 0); \
    }                                                                     \
    __builtin_amdgcn_s_setprio(0);
#define WAITV(COND)                                                       \
    if (COND) { asm volatile("s_waitcnt vmcnt(6)" ::: "memory"); }        \
    else      { asm volatile("s_waitcnt vmcnt(0)" ::: "memory"); }        \
    __builtin_amdgcn_sched_barrier(0);

    STAGE(0, 1, 0); STAGE(0, 1, 1); STAGE(0, 1, 2); STAGE(0, 1, 3);
    STAGE(0, 0, 0); STAGE(0, 0, 2); STAGE(0, 0, 1); STAGE(0, 0, 3);
    STAGE(1, 1, 0); STAGE(1, 1, 1); STAGE(1, 1, 2); STAGE(1, 1, 3);
    STAGE(1, 0, 0); STAGE(1, 0, 2);
    asm volatile("s_waitcnt vmcnt(6)" ::: "memory");
    __builtin_amdgcn_sched_barrier(0);
    __builtin_amdgcn_s_barrier();

    for (int i2 = 0; i2 < NT2; ++i2) {
        const int t1 = 2 * i2 + 1, tn0 = t1 + 1, tn1 = t1 + 2;
        const bool h0 = tn0 < NT, h1 = tn1 < NT;
        LOADB(LB0) LOADA(LA0, 0)
        STAGE(t1, 0, 1); STAGE(t1, 0, 3);
        DOMFMA(0)
        __builtin_amdgcn_s_barrier();
        LOADA(LA0, 1)
        if (h0) { STAGE(tn0, 1, 0); STAGE(tn0, 1, 1); }
        DOMFMA(1)
        __builtin_amdgcn_s_barrier();
        LOADA(LA0, 2)
        if (h0) { STAGE(tn0, 1, 2); STAGE(tn0, 1, 3); }
        DOMFMA(2)
        __builtin_amdgcn_s_barrier();
        LOADA(LA0, 3)
        if (h0) { STAGE(tn0, 0, 0); STAGE(tn0, 0, 2); }
        DOMFMA(3)
        WAITV(h0)
        __builtin_amdgcn_s_barrier();
        LOADB(LB1) LOADA(LA1, 0)
        if (h0) { STAGE(tn0, 0, 1); STAGE(tn0, 0, 3); }
        DOMFMA(0)
        __builtin_amdgcn_s_barrier();
        LOADA(LA1, 1)
        if (h1) { STAGE(tn1, 1, 0); STAGE(tn1, 1, 1); }
        DOMFMA(1)
        __builtin_amdgcn_s_barrier();
        LOADA(LA1, 2)
        if (h1) { STAGE(tn1, 1, 2); STAGE(tn1, 1, 3); }
        DOMFMA(2)
        __builtin_amdgcn_s_barrier();
        LOADA(LA1, 3)
        if (h1) { STAGE(tn1, 0, 0); STAGE(tn1, 0, 2); }
        DOMFMA(3)
        WAITV(h1)
        __builtin_amdgcn_s_barrier();
    }
    if (NT & 1) {
        LOADB(LB0) LOADA(LA0, 0) DOMFMA(0)
        __builtin_amdgcn_s_barrier();
        LOADA(LA0, 1) DOMFMA(1)
        __builtin_amdgcn_s_barrier();
        LOADA(LA0, 2) DOMFMA(2)
        __builtin_amdgcn_s_barrier();
        LOADA(LA0, 3) DOMFMA(3)
    }
#undef LOADB
#undef LOADA
#undef DOMFMA
#undef WAITV

    const float* biasp = bias + (size_t)bz * sbE;
#pragma unroll
    for (int mi = 0; mi < 8; ++mi) {
        const int rowb = m0 + wm * 128 + mi * 16 + hi * 4;
#pragma unroll
        for (int nj = 0; nj < 4; ++nj) {
            const int col = n0 + wn * 64 + nj * 16 + fr;
            const float bv = biasp[col];
#pragma unroll
            for (int r = 0; r < 4; ++r) {
                const int row = rowb + r;
                const size_t idx = (size_t)row * N + col;
                if (MODE == 0) {
                    ((u16*)Zv)[(size_t)bz * sZe + idx] = f2b(acc[mi][nj][r] + bv);
                } else if (MODE == 1) {
                    const float c = st[idx] + acc[mi][nj][r] + bv;
                    ((float*)Zv)[(size_t)bz * sZe + idx] = c;
                } else {
                    const float c = st[idx] + acc[mi][nj][r] + bv;
                    sum_o[idx] += c;
                    sq_o[idx] += c * c;
                }
            }
        }
    }
}

// ---------------- LayerNorm + GELU (+residual, +fused rew/done heads) --------
// One wave per row. bf16 params (preconverted). RES: h += residual.
// FIN: also dot final h with W_rew/W_done (bf16), sigmoid, atomic into sums.
template<int RES, int FIN>
__global__ __launch_bounds__(256) void k_ln(
    const u16* __restrict__ z, u16* __restrict__ h,
    const u16* __restrict__ g, const u16* __restrict__ be, int egb,
    const u16* __restrict__ wr, const u16* __restrict__ wd,
    const float* __restrict__ br, const float* __restrict__ bd,
    float* __restrict__ sum_rew, float* __restrict__ sum_done)
{
    const int lane = threadIdx.x & 63;
    const int w = threadIdx.x >> 6;
    const int e = blockIdx.z;
    const int row = blockIdx.x * 4 + w;
    const size_t base = ((size_t)e * B_SZ + row) * H_DIM;
    const u16* zr = z + base;
    u16* hr = h + base;
    const u16* gp = g + (size_t)e * egb;
    const u16* bp = be + (size_t)e * egb;

    u16x8 zv[4], gv[4], bv[4], hv[4], wrv[4], wdv[4];
#pragma unroll
    for (int j = 0; j < 4; ++j) {
        const int c = j * 512 + lane * 8;
        zv[j] = *(const u16x8*)&zr[c];
        gv[j] = *(const u16x8*)&gp[c];
        bv[j] = *(const u16x8*)&bp[c];
        if (RES) hv[j] = *(const u16x8*)&hr[c];
        if (FIN) {
            wrv[j] = *(const u16x8*)&wr[(size_t)e * H_DIM + c];
            wdv[j] = *(const u16x8*)&wd[(size_t)e * H_DIM + c];
        }
    }
    float s = 0.f, q = 0.f;
#pragma unroll
    for (int j = 0; j < 4; ++j)
#pragma unroll
        for (int k = 0; k < 8; ++k) {
            const float f = b2f(zv[j][k]); s += f; q += f * f;
        }
#pragma unroll
    for (int o = 32; o; o >>= 1) { s += __shfl_xor(s, o); q += __shfl_xor(q, o); }
    const float mu = s * (1.0f / H_DIM);
    const float rsg = rsqrtf(q * (1.0f / H_DIM) - mu * mu + 1e-5f);

    float dr = 0.f, dd = 0.f;
#pragma unroll
    for (int j = 0; j < 4; ++j) {
        u16x8 ov;
#pragma unroll
        for (int k = 0; k < 8; ++k) {
            const float y = (b2f(zv[j][k]) - mu) * rsg * b2f(gv[j][k]) + b2f(bv[j][k]);
            float ge = gelu_f(y);
            if (RES) ge += b2f(hv[j][k]);
            if (FIN) { dr += ge * b2f(wrv[j][k]); dd += ge * b2f(wdv[j][k]); }
            ov[k] = f2b(ge);
        }
        *(u16x8*)&hr[j * 512 + lane * 8] = ov;
    }
    if (FIN) {
#pragma unroll
        for (int o = 32; o; o >>= 1) { dr += __shfl_xor(dr, o); dd += __shfl_xor(dd, o); }
        if (lane == 0) {
            atomicAdd(&sum_rew[row], dr + br[e]);
            atomicAdd(&sum_done[row], 1.0f / (1.0f + __expf(-(dd + bd[e]))));
        }
    }
}

// ---------------- reward/done heads (EB==1 fallback only) --------------------
__global__ __launch_bounds__(256) void k_rewdone(
    const u16* __restrict__ hB, const float* __restrict__ Wr, const float* __restrict__ Wd,
    const float* __restrict__ br, const float* __restrict__ bd,
    float* __restrict__ sum_rew, float* __restrict__ sum_done)
{
    const int e = blockIdx.z;
    const int lane = threadIdx.x & 63;
    const int b = blockIdx.x * 4 + (threadIdx.x >> 6);
    const u16* hrow = hB + ((size_t)e * B_SZ + b) * H_DIM;
    const float* wr_ = Wr + (size_t)e * H_DIM;
    const float* wd_ = Wd + (size_t)e * H_DIM;
    float dr = 0.f, dd = 0.f;
#pragma unroll
    for (int j = 0; j < 4; ++j) {
        const int o = j * 512 + lane * 8;
        u16x8 hv = *(const u16x8*)&hrow[o];
#pragma unroll
        for (int k = 0; k < 8; ++k) {
            const float f = b2f(hv[k]);
            dr += f * wr_[o + k];
            dd += f * wd_[o + k];
        }
    }
#pragma unroll
    for (int o = 32; o; o >>= 1) { dr += __shfl_xor(dr, o); dd += __shfl_xor(dd, o); }
    if (lane == 0) {
        atomicAdd(&sum_rew[b], dr + br[e]);
        atomicAdd(&sum_done[b], 1.0f / (1.0f + expf(-(dd + bd[e]))));
    }
}

// ---------------- finalize: mean/var over E ---------------------------------
template<int FB>
__global__ __launch_bounds__(256) void k_final(
    const float* __restrict__ P, const float* __restrict__ sum_st,
    const float* __restrict__ sq_st, const float* __restrict__ sum_rew,
    const float* __restrict__ sum_done, float* __restrict__ out)
{
    const int b = blockIdx.x, t = threadIdx.x;
    float vs = 0.f;
#pragma unroll
    for (int k = 0; k < 2; ++k) {
        const int s = t + k * 256;
        const size_t i = (size_t)b * S_DIM + s;
        float S1, S2;
        if (FB == 0) {
            S1 = 0.f; S2 = 0.f;
#pragma unroll
            for (int e = 0; e < 8; ++e) {
                const float c = P[(size_t)e * OUT_MS + i];
                S1 += c; S2 += c * c;
            }
        } else { S1 = sum_st[i]; S2 = sq_st[i]; }
        out[i] = S1 * 0.125f;
        vs += (S2 - S1 * S1 * 0.125f) * (1.0f / 7.0f);
    }
#pragma unroll
    for (int o = 32; o; o >>= 1) vs += __shfl_xor(vs, o);
    __shared__ float rv[4];
    if ((t & 63) == 0) rv[t >> 6] = vs;
    __syncthreads();
    if (t == 0) {
        const float tot = rv[0] + rv[1] + rv[2] + rv[3];
        out[OUT_MS + b] = sum_rew[b] * 0.125f;
        out[OUT_MS + B_SZ + b] = sum_done[b] * 0.125f;
        out[OUT_MS + 2 * B_SZ + b] = tot * (1.0f / S_DIM);
    }
}

extern "C" void kernel_launch(void* const* d_in, const int* in_sizes, int n_in,
                              void* d_out, int out_size, void* d_ws, size_t ws_size,
                              hipStream_t stream) {
    (void)in_sizes; (void)n_in; (void)out_size;
    const float* state   = (const float*)d_in[0];
    const float* action  = (const float*)d_in[1];
    const float* W_in    = (const float*)d_in[2];
    const float* b_in    = (const float*)d_in[3];
    const float* g_in    = (const float*)d_in[4];
    const float* be_in   = (const float*)d_in[5];
    const float* W_h     = (const float*)d_in[6];
    const float* b_h     = (const float*)d_in[7];
    const float* g_h     = (const float*)d_in[8];
    const float* be_h    = (const float*)d_in[9];
    const float* W_state = (const float*)d_in[10];
    const float* b_state = (const float*)d_in[11];
    const float* W_rew   = (const float*)d_in[12];
    const float* b_rew   = (const float*)d_in[13];
    const float* W_done  = (const float*)d_in[14];
    const float* b_done  = (const float*)d_in[15];
    float* out = (float*)d_out;

    char* ws = (char*)d_ws;
    size_t off = 0;
    auto alloc = [&](size_t bytes) -> void* {
        void* p = ws + off; off += (bytes + 255) & ~((size_t)255); return p;
    };
    const size_t BH = (size_t)B_SZ * H_DIM;       // 16777216
    u16*   xb      = (u16*)alloc((size_t)B_SZ * KIN * 2);
    u16*   Wt_in   = (u16*)alloc((size_t)8 * H_DIM * KIN * 2);
    u16*   Wt_h    = (u16*)alloc((size_t)24 * H_DIM * H_DIM * 2);
    u16*   Wt_st   = (u16*)alloc((size_t)8 * S_DIM * H_DIM * 2);
    u16*   gb16    = (u16*)alloc((size_t)163840 * 2);
    float* sum_st  = (float*)alloc((size_t)B_SZ * S_DIM * 4);
    float* sq_st   = (float*)alloc((size_t)B_SZ * S_DIM * 4);
    float* sum_rew = (float*)alloc((size_t)B_SZ * 4);
    float* sum_done= (float*)alloc((size_t)B_SZ * 4);
    const size_t fixed = off;
    const int EB = (ws_size >= fixed + 2ULL * 8 * BH * 2) ? 8 : 1;
    u16*   hbuf    = (u16*)alloc((size_t)EB * BH * 2);
    u16*   zbuf    = (u16*)alloc((size_t)EB * BH * 2);
    float* Pbuf    = (float*)zbuf;   // batched: f32 next_states alias (dead zbuf)

    u16* g16_in = gb16;
    u16* be16_in = gb16 + 16384;
    u16* g16_h = gb16 + 32768;
    u16* be16_h = gb16 + 81920;
    u16* wr16 = gb16 + 131072;
    u16* wd16 = gb16 + 147456;

    if (EB == 8) {
        hipMemsetAsync(sum_rew, 0, 2 * (size_t)B_SZ * 4, stream);
    } else {
        hipMemsetAsync(sum_st, 0, (2 * (size_t)B_SZ * S_DIM + 2 * B_SZ) * 4, stream);
    }

    k_concat<<<dim3((B_SZ * KIN) / 256), dim3(256), 0, stream>>>(state, action, xb);
    k_cast<<<dim3(640), dim3(256), 0, stream>>>(g_in, be_in, g_h, be_h, W_rew, W_done, gb16);
    k_transpose<<<dim3(H_DIM / 32, KIN / 32, 8),    dim3(32, 8), 0, stream>>>(W_in, Wt_in, KIN, H_DIM);
    k_transpose<<<dim3(H_DIM / 32, H_DIM / 32, 24), dim3(32, 8), 0, stream>>>(W_h, Wt_h, H_DIM, H_DIM);
    k_transpose<<<dim3(S_DIM / 32, H_DIM / 32, 8),  dim3(32, 8), 0, stream>>>(W_state, Wt_st, H_DIM, S_DIM);

    for (int e0 = 0; e0 < 8; e0 += EB) {
        const dim3 gH(32, 8, EB), gS(32, 2, EB), gL(2048, 1, EB);
        k_gemm256<0><<<gH, 512, 0, stream>>>(
            xb, 0, Wt_in + (size_t)e0 * H_DIM * KIN, (size_t)H_DIM * KIN,
            b_in + (size_t)e0 * H_DIM, H_DIM, zbuf, BH,
            nullptr, nullptr, nullptr, H_DIM, KIN);
        k_ln<0, 0><<<gL, 256, 0, stream>>>(zbuf, hbuf,
            g16_in + (size_t)e0 * H_DIM, be16_in + (size_t)e0 * H_DIM, H_DIM,
            nullptr, nullptr, nullptr, nullptr, nullptr, nullptr);
        for (int l = 0; l < 3; ++l) {
            k_gemm256<0><<<gH, 512, 0, stream>>>(
                hbuf, BH, Wt_h + ((size_t)e0 * 3 + l) * H_DIM * H_DIM, (size_t)3 * H_DIM * H_DIM,
                b_h + (size_t)(e0 * 3 + l) * H_DIM, 3 * H_DIM, zbuf, BH,
                nullptr, nullptr, nullptr, H_DIM, H_DIM);
            if (EB == 8 && l == 2) {
                k_ln<1, 1><<<gL, 256, 0, stream>>>(zbuf, hbuf,
                    g16_h + (size_t)(e0 * 3 + l) * H_DIM, be16_h + (size_t)(e0 * 3 + l) * H_DIM,
                    3 * H_DIM, wr16, wd16, b_rew, b_done, sum_rew, sum_done);
            } else {
                k_ln<1, 0><<<gL, 256, 0, stream>>>(zbuf, hbuf,
                    g16_h + (size_t)(e0 * 3 + l) * H_DIM, be16_h + (size_t)(e0 * 3 + l) * H_DIM,
                    3 * H_DIM, nullptr, nullptr, nullptr, nullptr, nullptr, nullptr);
            }
        }
        if (EB == 8) {
            k_gemm256<1><<<gS, 512, 0, stream>>>(
                hbuf, BH, Wt_st, (size_t)S_DIM * H_DIM,
                b_state, S_DIM, (void*)Pbuf, (size_t)OUT_MS,
                state, nullptr, nullptr, S_DIM, H_DIM);
        } else {
            k_gemm256<2><<<gS, 512, 0, stream>>>(
                hbuf, BH, Wt_st + (size_t)e0 * S_DIM * H_DIM, (size_t)S_DIM * H_DIM,
                b_state + (size_t)e0 * S_DIM, S_DIM, (void*)zbuf, 0,
                state, sum_st, sq_st, S_DIM, H_DIM);
            k_rewdone<<<gL, 256, 0, stream>>>(hbuf,
                W_rew + (size_t)e0 * H_DIM, W_done + (size_t)e0 * H_DIM,
                b_rew + e0, b_done + e0, sum_rew, sum_done);
        }
    }
    if (EB == 8)
        k_final<0><<<dim3(B_SZ), dim3(256), 0, stream>>>(Pbuf, nullptr, nullptr, sum_rew, sum_done, out);
    else
        k_final<1><<<dim3(B_SZ), dim3(256), 0, stream>>>(nullptr, sum_st, sq_st, sum_rew, sum_done, out);
}